// Round 2
// baseline (1155.906 us; speedup 1.0000x reference)
//
#include <hip/hip_runtime.h>

// GraphSAGE layer: out = relu([x, mean-agg(x[src]->dst)] @ W^T + b)
// N=50000 nodes, E=600000 edges, D=128.
//
// Phase 1: scatter-add x[src] rows into d_out (used as neigh_sum buffer) + deg atomics.
// Phase 2: finalize in place: d_out[n] = deg>0 ? d_out[n]/deg : x[n]   (= neigh_agg)
// Phase 3: GEMM in-place on d_out. The agg tile is staged into LDS and a
//          __syncthreads() separates ALL aliased global reads from ANY store,
//          fixing the round-1 cross-wave read-after-write race.

#define D 128
#define NT 32   // nodes per block in gemm
#define NTT 16  // nodes per thread (block = 256 thr: 128 j-lanes x 2 node-halves)

__global__ __launch_bounds__(256) void sage_scatter(
    const float* __restrict__ x, const int* __restrict__ src,
    const int* __restrict__ dst, float* out_sum, int* deg, int n_edges)
{
    long long gid = (long long)blockIdx.x * 256 + threadIdx.x;
    long long total = (long long)n_edges * 32;  // one float4 per thread
    if (gid >= total) return;
    int e  = (int)(gid >> 5);
    int d4 = (int)(gid & 31);
    int s  = src[e];
    int dd = dst[e];
    float4 xv = ((const float4*)x)[s * 32 + d4];
    float* o = out_sum + (long long)dd * D + d4 * 4;
    atomicAdd(o + 0, xv.x);
    atomicAdd(o + 1, xv.y);
    atomicAdd(o + 2, xv.z);
    atomicAdd(o + 3, xv.w);
    if (d4 == 0) atomicAdd(deg + dd, 1);
}

__global__ __launch_bounds__(256) void sage_finalize(
    const float* __restrict__ x, const int* __restrict__ deg,
    float* out, int n_nodes)
{
    int gid = blockIdx.x * 256 + threadIdx.x;  // float4 element index
    int total = n_nodes * 32;
    if (gid >= total) return;
    int n = gid >> 5;
    int dg = deg[n];
    float4 v = ((float4*)out)[gid];
    if (dg > 0) {
        float inv = 1.0f / (float)dg;
        v.x *= inv; v.y *= inv; v.z *= inv; v.w *= inv;
    } else {
        v = ((const float4*)x)[gid];
    }
    ((float4*)out)[gid] = v;
}

// agg aliases out (same buffer). Both tiles are staged into LDS; the barrier
// guarantees every aliased global read completes before any store.
__global__ __launch_bounds__(256) void sage_gemm(
    const float* __restrict__ x, const float* __restrict__ W,
    const float* __restrict__ b, const float* agg, float* out, int n_nodes)
{
    __shared__ float4 sx[NT * 32];   // 32 rows x 32 float4 = 16 KB
    __shared__ float4 sa[NT * 32];   // 16 KB

    int tid = threadIdx.x;
    int base_row = blockIdx.x * NT;

    // Stage x and agg tiles (coalesced float4 loads; clamp OOB rows).
    for (int i = tid; i < NT * 32; i += 256) {
        int r = i >> 5, c = i & 31;
        int n = base_row + r; if (n >= n_nodes) n = n_nodes - 1;
        sx[i] = ((const float4*)x)[(long long)n * 32 + c];
        sa[i] = ((const float4*)agg)[(long long)n * 32 + c];
    }
    __syncthreads();   // all aliased reads done before any store below

    int j   = tid & 127;   // output column -> coalesced store
    int sub = tid >> 7;    // node half
    int rbase = sub * NTT;

    const float4* W4 = (const float4*)W;   // W row j = 64 float4s
    float acc[NTT];
#pragma unroll
    for (int i = 0; i < NTT; ++i) acc[i] = 0.f;

#pragma unroll 4
    for (int k4 = 0; k4 < 32; ++k4) {
        float4 wx = W4[j * 64 + k4];        // W[j][k]      (x part)
        float4 wa = W4[j * 64 + 32 + k4];   // W[j][128+k]  (agg part)
#pragma unroll
        for (int nn = 0; nn < NTT; ++nn) {
            float4 hx = sx[(rbase + nn) * 32 + k4];  // LDS broadcast across j-lanes
            float4 ha = sa[(rbase + nn) * 32 + k4];
            acc[nn] += wx.x * hx.x + wx.y * hx.y + wx.z * hx.z + wx.w * hx.w
                     + wa.x * ha.x + wa.y * ha.y + wa.z * ha.z + wa.w * ha.w;
        }
    }

    float bj = b[j];
#pragma unroll
    for (int nn = 0; nn < NTT; ++nn) {
        int n = base_row + rbase + nn;
        if (n < n_nodes) {
            float v = acc[nn] + bj;
            out[(long long)n * D + j] = v > 0.f ? v : 0.f;
        }
    }
}

extern "C" void kernel_launch(void* const* d_in, const int* in_sizes, int n_in,
                              void* d_out, int out_size, void* d_ws, size_t ws_size,
                              hipStream_t stream) {
    const float* x  = (const float*)d_in[0];
    const float* W  = (const float*)d_in[1];
    const float* b  = (const float*)d_in[2];
    const int* src  = (const int*)d_in[3];
    const int* dst  = (const int*)d_in[4];
    float* out = (float*)d_out;

    int n_nodes = in_sizes[0] / D;
    int n_edges = in_sizes[3];
    int* deg = (int*)d_ws;  // 50000 ints = 200 KB of scratch

    // Zero the sum buffer (d_out doubles as neigh_sum) and degrees.
    hipMemsetAsync(d_out, 0, (size_t)out_size * sizeof(float), stream);
    hipMemsetAsync(deg, 0, (size_t)n_nodes * sizeof(int), stream);

    {   // scatter: one float4 per thread
        long long total = (long long)n_edges * 32;
        int blocks = (int)((total + 255) / 256);
        sage_scatter<<<blocks, 256, 0, stream>>>(x, src, dst, out, deg, n_edges);
    }
    {   // finalize mean / fallback-to-x
        int total = n_nodes * 32;
        int blocks = (total + 255) / 256;
        sage_finalize<<<blocks, 256, 0, stream>>>(x, deg, out, n_nodes);
    }
    {   // fused concat + GEMM + bias + relu (in place on d_out, LDS-staged)
        int blocks = (n_nodes + NT - 1) / NT;
        sage_gemm<<<blocks, 256, 0, stream>>>(x, W, b, out, out, n_nodes);
    }
}

// Round 8
// 215.759 us; speedup vs baseline: 5.3574x; 5.3574x over previous
//
#include <hip/hip_runtime.h>

// GraphSAGE layer: out = relu([x, mean-agg(x[src]->dst)] @ W^T + b)
// N=50000 nodes, E=600000 edges, D=128.
//
// CSR path (round 3 kernel; rounds 3-7 all died on the same unresponsive
// container before compile/run — identical resubmit): build dst-bucketed edge
// list on device (int atomics only), then gather-sum per node (no fp atomics),
// then fused GEMM in-place on d_out. Fallback to round-2 fp-atomic path if ws
// is too small.

#define D 128
#define NT 32   // nodes per block in gemm
#define NTT 16  // nodes per thread in gemm

// ---------------- CSR build ----------------

__global__ __launch_bounds__(256) void edge_count(
    const int* __restrict__ dst, int* deg, int n_edges)
{
    int e = blockIdx.x * 256 + threadIdx.x;
    if (e < n_edges) atomicAdd(deg + dst[e], 1);
}

// Inclusive scan of deg per 256-block; result into off; block totals into bsum.
__global__ __launch_bounds__(256) void scan_a(
    const int* __restrict__ deg, int* off, int* bsum, int n)
{
    __shared__ int tmp[256];
    int i = blockIdx.x * 256 + threadIdx.x;
    int v = (i < n) ? deg[i] : 0;
    tmp[threadIdx.x] = v;
    __syncthreads();
    for (int s = 1; s < 256; s <<= 1) {
        int t = (threadIdx.x >= s) ? tmp[threadIdx.x - s] : 0;
        __syncthreads();
        tmp[threadIdx.x] += t;
        __syncthreads();
    }
    if (i < n) off[i] = tmp[threadIdx.x];
    if (threadIdx.x == 255) bsum[blockIdx.x] = tmp[255];
}

// Inclusive scan of block sums (nb <= 256).
__global__ __launch_bounds__(256) void scan_b(int* bsum, int nb)
{
    __shared__ int tmp[256];
    int v = (threadIdx.x < nb) ? bsum[threadIdx.x] : 0;
    tmp[threadIdx.x] = v;
    __syncthreads();
    for (int s = 1; s < 256; s <<= 1) {
        int t = (threadIdx.x >= s) ? tmp[threadIdx.x - s] : 0;
        __syncthreads();
        tmp[threadIdx.x] += t;
        __syncthreads();
    }
    if (threadIdx.x < nb) bsum[threadIdx.x] = tmp[threadIdx.x];
}

// off[i] (currently block-local inclusive) -> global exclusive; cursor copy.
__global__ __launch_bounds__(256) void scan_c(
    const int* __restrict__ deg, const int* __restrict__ bsum,
    int* off, int* cursor, int n)
{
    int i = blockIdx.x * 256 + threadIdx.x;
    if (i >= n) return;
    int add = (blockIdx.x > 0) ? bsum[blockIdx.x - 1] : 0;
    int e = off[i] - deg[i] + add;
    off[i] = e;
    cursor[i] = e;
}

__global__ __launch_bounds__(256) void edge_fill(
    const int* __restrict__ src, const int* __restrict__ dst,
    int* cursor, int* edge_src, int n_edges)
{
    int e = blockIdx.x * 256 + threadIdx.x;
    if (e < n_edges) {
        int p = atomicAdd(cursor + dst[e], 1);
        edge_src[p] = src[e];
    }
}

// ---------------- gather (one wave per node) ----------------

__global__ __launch_bounds__(256) void sage_gather(
    const float* __restrict__ x, const int* __restrict__ edge_src,
    const int* __restrict__ off, const int* __restrict__ deg,
    float* __restrict__ agg, int n_nodes)
{
    int wid  = threadIdx.x >> 6;
    int lane = threadIdx.x & 63;
    int n = blockIdx.x * 4 + wid;
    if (n >= n_nodes) return;
    int dg   = deg[n];
    int base = off[n];
    const float2* X2 = (const float2*)x;

    float sx = 0.f, sy = 0.f;
    int j = 0;
    for (; j + 1 < dg; j += 2) {
        int s0 = edge_src[base + j];
        int s1 = edge_src[base + j + 1];
        float2 a = X2[(long long)s0 * 64 + lane];
        float2 c = X2[(long long)s1 * 64 + lane];
        sx += a.x + c.x;
        sy += a.y + c.y;
    }
    if (j < dg) {
        int s0 = edge_src[base + j];
        float2 a = X2[(long long)s0 * 64 + lane];
        sx += a.x; sy += a.y;
    }
    float2 r;
    if (dg > 0) {
        float inv = 1.0f / (float)dg;
        r.x = sx * inv; r.y = sy * inv;
    } else {
        r = X2[(long long)n * 64 + lane];
    }
    ((float2*)agg)[(long long)n * 64 + lane] = r;
}

// ---------------- fallback fp-atomic path (round 2, proven) ----------------

__global__ __launch_bounds__(256) void sage_scatter(
    const float* __restrict__ x, const int* __restrict__ src,
    const int* __restrict__ dst, float* out_sum, int* deg, int n_edges)
{
    long long gid = (long long)blockIdx.x * 256 + threadIdx.x;
    long long total = (long long)n_edges * 32;
    if (gid >= total) return;
    int e  = (int)(gid >> 5);
    int d4 = (int)(gid & 31);
    int s  = src[e];
    int dd = dst[e];
    float4 xv = ((const float4*)x)[s * 32 + d4];
    float* o = out_sum + (long long)dd * D + d4 * 4;
    atomicAdd(o + 0, xv.x);
    atomicAdd(o + 1, xv.y);
    atomicAdd(o + 2, xv.z);
    atomicAdd(o + 3, xv.w);
    if (d4 == 0) atomicAdd(deg + dd, 1);
}

__global__ __launch_bounds__(256) void sage_finalize(
    const float* __restrict__ x, const int* __restrict__ deg,
    float* out, int n_nodes)
{
    int gid = blockIdx.x * 256 + threadIdx.x;
    int total = n_nodes * 32;
    if (gid >= total) return;
    int n = gid >> 5;
    int dg = deg[n];
    float4 v = ((float4*)out)[gid];
    if (dg > 0) {
        float inv = 1.0f / (float)dg;
        v.x *= inv; v.y *= inv; v.z *= inv; v.w *= inv;
    } else {
        v = ((const float4*)x)[gid];
    }
    ((float4*)out)[gid] = v;
}

// ---------------- fused GEMM (in-place on d_out, LDS-staged) ----------------

__global__ __launch_bounds__(256) void sage_gemm(
    const float* __restrict__ x, const float* __restrict__ W,
    const float* __restrict__ b, const float* agg, float* out, int n_nodes)
{
    __shared__ float4 sx[NT * 32];
    __shared__ float4 sa[NT * 32];

    int tid = threadIdx.x;
    int base_row = blockIdx.x * NT;

    for (int i = tid; i < NT * 32; i += 256) {
        int r = i >> 5, c = i & 31;
        int n = base_row + r; if (n >= n_nodes) n = n_nodes - 1;
        sx[i] = ((const float4*)x)[(long long)n * 32 + c];
        sa[i] = ((const float4*)agg)[(long long)n * 32 + c];
    }
    __syncthreads();   // all aliased reads done before any store below

    int j   = tid & 127;
    int sub = tid >> 7;
    int rbase = sub * NTT;

    const float4* W4 = (const float4*)W;
    float acc[NTT];
#pragma unroll
    for (int i = 0; i < NTT; ++i) acc[i] = 0.f;

#pragma unroll 4
    for (int k4 = 0; k4 < 32; ++k4) {
        float4 wx = W4[j * 64 + k4];
        float4 wa = W4[j * 64 + 32 + k4];
#pragma unroll
        for (int nn = 0; nn < NTT; ++nn) {
            float4 hx = sx[(rbase + nn) * 32 + k4];
            float4 ha = sa[(rbase + nn) * 32 + k4];
            acc[nn] += wx.x * hx.x + wx.y * hx.y + wx.z * hx.z + wx.w * hx.w
                     + wa.x * ha.x + wa.y * ha.y + wa.z * ha.z + wa.w * ha.w;
        }
    }

    float bj = b[j];
#pragma unroll
    for (int nn = 0; nn < NTT; ++nn) {
        int n = base_row + rbase + nn;
        if (n < n_nodes) {
            float v = acc[nn] + bj;
            out[(long long)n * D + j] = v > 0.f ? v : 0.f;
        }
    }
}

extern "C" void kernel_launch(void* const* d_in, const int* in_sizes, int n_in,
                              void* d_out, int out_size, void* d_ws, size_t ws_size,
                              hipStream_t stream) {
    const float* x  = (const float*)d_in[0];
    const float* W  = (const float*)d_in[1];
    const float* b  = (const float*)d_in[2];
    const int* src  = (const int*)d_in[3];
    const int* dst  = (const int*)d_in[4];
    float* out = (float*)d_out;

    int n_nodes = in_sizes[0] / D;
    int n_edges = in_sizes[3];

    int n_pad = (n_nodes + 255) & ~255;
    int nblocks_scan = (n_nodes + 255) / 256;

    // ws layout (ints): deg | off | cursor | bsum(1024) | edge_src
    size_t need = ((size_t)3 * n_pad + 1024 + (size_t)n_edges) * sizeof(int);
    bool csr_ok = (ws_size >= need) && (nblocks_scan <= 256);

    int* deg = (int*)d_ws;

    if (csr_ok) {
        int* off      = deg + n_pad;
        int* cursor   = off + n_pad;
        int* bsum     = cursor + n_pad;
        int* edge_src = bsum + 1024;

        hipMemsetAsync(deg, 0, (size_t)n_nodes * sizeof(int), stream);

        int eblocks = (n_edges + 255) / 256;
        edge_count<<<eblocks, 256, 0, stream>>>(dst, deg, n_edges);
        scan_a<<<nblocks_scan, 256, 0, stream>>>(deg, off, bsum, n_nodes);
        scan_b<<<1, 256, 0, stream>>>(bsum, nblocks_scan);
        scan_c<<<nblocks_scan, 256, 0, stream>>>(deg, bsum, off, cursor, n_nodes);
        edge_fill<<<eblocks, 256, 0, stream>>>(src, dst, cursor, edge_src, n_edges);

        int gblocks = (n_nodes + 3) / 4;
        sage_gather<<<gblocks, 256, 0, stream>>>(x, edge_src, off, deg, out, n_nodes);
    } else {
        // fallback: fp-atomic scatter (round-2 path)
        hipMemsetAsync(d_out, 0, (size_t)out_size * sizeof(float), stream);
        hipMemsetAsync(deg, 0, (size_t)n_nodes * sizeof(int), stream);
        long long total = (long long)n_edges * 32;
        int blocks = (int)((total + 255) / 256);
        sage_scatter<<<blocks, 256, 0, stream>>>(x, src, dst, out, deg, n_edges);
        int fblocks = (n_nodes * 32 + 255) / 256;
        sage_finalize<<<fblocks, 256, 0, stream>>>(x, deg, out, n_nodes);
    }

    {   // fused concat + GEMM + bias + relu (in place on d_out, LDS-staged)
        int blocks = (n_nodes + NT - 1) / NT;
        sage_gemm<<<blocks, 256, 0, stream>>>(x, W, b, out, out, n_nodes);
    }
}

// Round 10
// 164.257 us; speedup vs baseline: 7.0372x; 1.3135x over previous
//
#include <hip/hip_runtime.h>

// GraphSAGE layer: out = relu([x, mean-agg(x[src]->dst)] @ W^T + b)
// N=50000 nodes, E=600000 edges, D=128.
//
// Round 9 kernel, identical resubmit (round-9 bench died on the same
// unresponsive container as rounds 3-7; never compiled/ran).
//   1. convert x (25.6MB) and W (128KB) to bf16 in ws
//   2. CSR build (int atomics only, proven round 8)
//   3. gather: wave/node, reads bf16 rows (256B/row), fp32 accum, bf16 agg out
//   4. GEMM: mfma_f32_16x16x32_bf16, 4 waves/block, 64 rows/block, no LDS;
//      A-frags and B-frags loaded directly from global (W_bf16 is L2-hot).
// Fallbacks: fp32 CSR path (round-8, measured 216us) then fp-atomic path.

#define D 128
#define NT 32
#define NTT 16

typedef short bf16x8 __attribute__((ext_vector_type(8)));
typedef float f32x4 __attribute__((ext_vector_type(4)));

__device__ __forceinline__ unsigned bf16_rne(float f) {
    unsigned u = __float_as_uint(f);
    return (u + 0x7FFFu + ((u >> 16) & 1u)) >> 16;
}
__device__ __forceinline__ unsigned pack2(float lo, float hi) {
    return bf16_rne(lo) | (bf16_rne(hi) << 16);
}

// ---------------- fp32 -> bf16 conversion (8 elems/thread) ----------------

__global__ __launch_bounds__(256) void f32_to_bf16_k(
    const float* __restrict__ in, unsigned short* __restrict__ out, int n8)
{
    int i = blockIdx.x * 256 + threadIdx.x;
    if (i >= n8) return;
    const float4* I = (const float4*)in;
    float4 a = I[2 * i], c = I[2 * i + 1];
    uint4 r;
    r.x = pack2(a.x, a.y); r.y = pack2(a.z, a.w);
    r.z = pack2(c.x, c.y); r.w = pack2(c.z, c.w);
    ((uint4*)out)[i] = r;
}

// ---------------- CSR build ----------------

__global__ __launch_bounds__(256) void edge_count(
    const int* __restrict__ dst, int* deg, int n_edges)
{
    int e = blockIdx.x * 256 + threadIdx.x;
    if (e < n_edges) atomicAdd(deg + dst[e], 1);
}

__global__ __launch_bounds__(256) void scan_a(
    const int* __restrict__ deg, int* off, int* bsum, int n)
{
    __shared__ int tmp[256];
    int i = blockIdx.x * 256 + threadIdx.x;
    int v = (i < n) ? deg[i] : 0;
    tmp[threadIdx.x] = v;
    __syncthreads();
    for (int s = 1; s < 256; s <<= 1) {
        int t = (threadIdx.x >= s) ? tmp[threadIdx.x - s] : 0;
        __syncthreads();
        tmp[threadIdx.x] += t;
        __syncthreads();
    }
    if (i < n) off[i] = tmp[threadIdx.x];
    if (threadIdx.x == 255) bsum[blockIdx.x] = tmp[255];
}

__global__ __launch_bounds__(256) void scan_b(int* bsum, int nb)
{
    __shared__ int tmp[256];
    int v = (threadIdx.x < nb) ? bsum[threadIdx.x] : 0;
    tmp[threadIdx.x] = v;
    __syncthreads();
    for (int s = 1; s < 256; s <<= 1) {
        int t = (threadIdx.x >= s) ? tmp[threadIdx.x - s] : 0;
        __syncthreads();
        tmp[threadIdx.x] += t;
        __syncthreads();
    }
    if (threadIdx.x < nb) bsum[threadIdx.x] = tmp[threadIdx.x];
}

__global__ __launch_bounds__(256) void scan_c(
    const int* __restrict__ deg, const int* __restrict__ bsum,
    int* off, int* cursor, int n)
{
    int i = blockIdx.x * 256 + threadIdx.x;
    if (i >= n) return;
    int add = (blockIdx.x > 0) ? bsum[blockIdx.x - 1] : 0;
    int e = off[i] - deg[i] + add;
    off[i] = e;
    cursor[i] = e;
}

__global__ __launch_bounds__(256) void edge_fill(
    const int* __restrict__ src, const int* __restrict__ dst,
    int* cursor, int* edge_src, int n_edges)
{
    int e = blockIdx.x * 256 + threadIdx.x;
    if (e < n_edges) {
        int p = atomicAdd(cursor + dst[e], 1);
        edge_src[p] = src[e];
    }
}

// ---------------- gather bf16 (one wave per node) ----------------

__global__ __launch_bounds__(256) void sage_gather_bf16(
    const unsigned short* __restrict__ xh, const int* __restrict__ edge_src,
    const int* __restrict__ off, const int* __restrict__ deg,
    unsigned short* __restrict__ ah, int n_nodes)
{
    int wid  = threadIdx.x >> 6;
    int lane = threadIdx.x & 63;
    int n = blockIdx.x * 4 + wid;
    if (n >= n_nodes) return;
    int dg   = deg[n];
    int base = off[n];
    const unsigned* X = (const unsigned*)xh;   // 2 bf16 per word, 64 words/row

    float sx = 0.f, sy = 0.f;   // lo, hi halves
    int j = 0;
    for (; j + 1 < dg; j += 2) {
        int s0 = edge_src[base + j];
        int s1 = edge_src[base + j + 1];
        unsigned a = X[s0 * 64 + lane];
        unsigned c = X[s1 * 64 + lane];
        sx += __uint_as_float(a << 16) + __uint_as_float(c << 16);
        sy += __uint_as_float(a & 0xFFFF0000u) + __uint_as_float(c & 0xFFFF0000u);
    }
    if (j < dg) {
        unsigned a = X[edge_src[base + j] * 64 + lane];
        sx += __uint_as_float(a << 16);
        sy += __uint_as_float(a & 0xFFFF0000u);
    }
    unsigned r;
    if (dg > 0) {
        float inv = 1.0f / (float)dg;
        r = pack2(sx * inv, sy * inv);
    } else {
        r = X[n * 64 + lane];
    }
    ((unsigned*)ah)[n * 64 + lane] = r;
}

// ---------------- MFMA GEMM: out = relu([x|agg] @ W^T + b) ----------------
// 4 waves/block, wave = 16 rows x 128 cols, 8 n-tiles of 16x16x32, K=256.
// A-frag: lane holds h[m0+(lane&15)][ks*32 + (lane>>4)*8 ..+8)  (16B global load)
// B-frag: lane holds W[nt*16+(lane&15)][k ..+8)                 (16B global load)
// C/D: col = lane&15, row = m0+(lane>>4)*4+reg  [measured m89/m91]

__global__ __launch_bounds__(256) void sage_gemm_mfma(
    const unsigned short* __restrict__ xh, const unsigned short* __restrict__ ah,
    const unsigned short* __restrict__ Wh, const float* __restrict__ bias,
    float* __restrict__ out, int n_nodes)
{
    int wid  = threadIdx.x >> 6;
    int lane = threadIdx.x & 63;
    int m0   = blockIdx.x * 64 + wid * 16;
    int arow = m0 + (lane & 15);
    if (arow >= n_nodes) arow = n_nodes - 1;   // clamp loads; stores guarded
    int ka = (lane >> 4) * 8;
    int jn = lane & 15;

    f32x4 acc[8] = {};

    const unsigned short* xr = xh + (long long)arow * 128;
    const unsigned short* ar = ah + (long long)arow * 128;

#pragma unroll
    for (int ks = 0; ks < 4; ++ks) {           // k = 0..127 (x half)
        bf16x8 af = *(const bf16x8*)(xr + ks * 32 + ka);
#pragma unroll
        for (int nt = 0; nt < 8; ++nt) {
            bf16x8 bf = *(const bf16x8*)(Wh + (long long)(nt * 16 + jn) * 256 + ks * 32 + ka);
            acc[nt] = __builtin_amdgcn_mfma_f32_16x16x32_bf16(af, bf, acc[nt], 0, 0, 0);
        }
    }
#pragma unroll
    for (int ks = 0; ks < 4; ++ks) {           // k = 128..255 (agg half)
        bf16x8 af = *(const bf16x8*)(ar + ks * 32 + ka);
#pragma unroll
        for (int nt = 0; nt < 8; ++nt) {
            bf16x8 bf = *(const bf16x8*)(Wh + (long long)(nt * 16 + jn) * 256 + 128 + ks * 32 + ka);
            acc[nt] = __builtin_amdgcn_mfma_f32_16x16x32_bf16(af, bf, acc[nt], 0, 0, 0);
        }
    }

    int orow0 = m0 + (lane >> 4) * 4;
#pragma unroll
    for (int nt = 0; nt < 8; ++nt) {
        int col = nt * 16 + jn;
        float bj = bias[col];
#pragma unroll
        for (int r = 0; r < 4; ++r) {
            int row = orow0 + r;
            if (row < n_nodes) {
                float v = acc[nt][r] + bj;
                out[(long long)row * 128 + col] = v > 0.f ? v : 0.f;
            }
        }
    }
}

// ---------------- fp32 fallback kernels (round-8 proven) ----------------

__global__ __launch_bounds__(256) void sage_gather(
    const float* __restrict__ x, const int* __restrict__ edge_src,
    const int* __restrict__ off, const int* __restrict__ deg,
    float* __restrict__ agg, int n_nodes)
{
    int wid  = threadIdx.x >> 6;
    int lane = threadIdx.x & 63;
    int n = blockIdx.x * 4 + wid;
    if (n >= n_nodes) return;
    int dg   = deg[n];
    int base = off[n];
    const float2* X2 = (const float2*)x;

    float sx = 0.f, sy = 0.f;
    int j = 0;
    for (; j + 1 < dg; j += 2) {
        int s0 = edge_src[base + j];
        int s1 = edge_src[base + j + 1];
        float2 a = X2[(long long)s0 * 64 + lane];
        float2 c = X2[(long long)s1 * 64 + lane];
        sx += a.x + c.x;
        sy += a.y + c.y;
    }
    if (j < dg) {
        float2 a = X2[(long long)edge_src[base + j] * 64 + lane];
        sx += a.x; sy += a.y;
    }
    float2 r;
    if (dg > 0) {
        float inv = 1.0f / (float)dg;
        r.x = sx * inv; r.y = sy * inv;
    } else {
        r = X2[(long long)n * 64 + lane];
    }
    ((float2*)agg)[(long long)n * 64 + lane] = r;
}

__global__ __launch_bounds__(256) void sage_scatter(
    const float* __restrict__ x, const int* __restrict__ src,
    const int* __restrict__ dst, float* out_sum, int* deg, int n_edges)
{
    long long gid = (long long)blockIdx.x * 256 + threadIdx.x;
    long long total = (long long)n_edges * 32;
    if (gid >= total) return;
    int e  = (int)(gid >> 5);
    int d4 = (int)(gid & 31);
    int s  = src[e];
    int dd = dst[e];
    float4 xv = ((const float4*)x)[s * 32 + d4];
    float* o = out_sum + (long long)dd * D + d4 * 4;
    atomicAdd(o + 0, xv.x);
    atomicAdd(o + 1, xv.y);
    atomicAdd(o + 2, xv.z);
    atomicAdd(o + 3, xv.w);
    if (d4 == 0) atomicAdd(deg + dd, 1);
}

__global__ __launch_bounds__(256) void sage_finalize(
    const float* __restrict__ x, const int* __restrict__ deg,
    float* out, int n_nodes)
{
    int gid = blockIdx.x * 256 + threadIdx.x;
    int total = n_nodes * 32;
    if (gid >= total) return;
    int n = gid >> 5;
    int dg = deg[n];
    float4 v = ((float4*)out)[gid];
    if (dg > 0) {
        float inv = 1.0f / (float)dg;
        v.x *= inv; v.y *= inv; v.z *= inv; v.w *= inv;
    } else {
        v = ((const float4*)x)[gid];
    }
    ((float4*)out)[gid] = v;
}

__global__ __launch_bounds__(256) void sage_gemm(
    const float* __restrict__ x, const float* __restrict__ W,
    const float* __restrict__ b, const float* agg, float* out, int n_nodes)
{
    __shared__ float4 sx[NT * 32];
    __shared__ float4 sa[NT * 32];

    int tid = threadIdx.x;
    int base_row = blockIdx.x * NT;

    for (int i = tid; i < NT * 32; i += 256) {
        int r = i >> 5, c = i & 31;
        int n = base_row + r; if (n >= n_nodes) n = n_nodes - 1;
        sx[i] = ((const float4*)x)[(long long)n * 32 + c];
        sa[i] = ((const float4*)agg)[(long long)n * 32 + c];
    }
    __syncthreads();

    int j   = tid & 127;
    int sub = tid >> 7;
    int rbase = sub * NTT;

    const float4* W4 = (const float4*)W;
    float acc[NTT];
#pragma unroll
    for (int i = 0; i < NTT; ++i) acc[i] = 0.f;

#pragma unroll 4
    for (int k4 = 0; k4 < 32; ++k4) {
        float4 wx = W4[j * 64 + k4];
        float4 wa = W4[j * 64 + 32 + k4];
#pragma unroll
        for (int nn = 0; nn < NTT; ++nn) {
            float4 hx = sx[(rbase + nn) * 32 + k4];
            float4 ha = sa[(rbase + nn) * 32 + k4];
            acc[nn] += wx.x * hx.x + wx.y * hx.y + wx.z * hx.z + wx.w * hx.w
                     + wa.x * ha.x + wa.y * ha.y + wa.z * ha.z + wa.w * ha.w;
        }
    }

    float bj = b[j];
#pragma unroll
    for (int nn = 0; nn < NTT; ++nn) {
        int n = base_row + rbase + nn;
        if (n < n_nodes) {
            float v = acc[nn] + bj;
            out[(long long)n * D + j] = v > 0.f ? v : 0.f;
        }
    }
}

extern "C" void kernel_launch(void* const* d_in, const int* in_sizes, int n_in,
                              void* d_out, int out_size, void* d_ws, size_t ws_size,
                              hipStream_t stream) {
    const float* x  = (const float*)d_in[0];
    const float* W  = (const float*)d_in[1];
    const float* b  = (const float*)d_in[2];
    const int* src  = (const int*)d_in[3];
    const int* dst  = (const int*)d_in[4];
    float* out = (float*)d_out;

    int n_nodes = in_sizes[0] / D;
    int n_edges = in_sizes[3];

    int n_pad = (n_nodes + 255) & ~255;
    int e_pad = (n_edges + 3) & ~3;
    int nblocks_scan = (n_nodes + 255) / 256;

    // ws layout (ints): deg | off | cursor | bsum(1024) | edge_src(e_pad)
    //   then (bf16 path): x_bf16 (N*128 u16) | agg_bf16 (N*128 u16) | W_bf16 (32768 u16)
    size_t need_csr  = ((size_t)3 * n_pad + 1024 + (size_t)e_pad) * sizeof(int);
    size_t need_bf16 = need_csr + ((size_t)n_nodes * D * 2 + 32768) * sizeof(unsigned short);
    bool scan_ok = (nblocks_scan <= 256);
    bool bf16_ok = scan_ok && (ws_size >= need_bf16);
    bool csr_ok  = scan_ok && (ws_size >= need_csr);

    int* deg = (int*)d_ws;
    int* off      = deg + n_pad;
    int* cursor   = off + n_pad;
    int* bsum     = cursor + n_pad;
    int* edge_src = bsum + 1024;

    if (bf16_ok) {
        unsigned short* xh = (unsigned short*)(edge_src + e_pad);
        unsigned short* ah = xh + (size_t)n_nodes * D;
        unsigned short* Wh = ah + (size_t)n_nodes * D;

        hipMemsetAsync(deg, 0, (size_t)n_nodes * sizeof(int), stream);

        // conversions
        int x8 = n_nodes * D / 8;
        f32_to_bf16_k<<<(x8 + 255) / 256, 256, 0, stream>>>(x, xh, x8);
        f32_to_bf16_k<<<(4096 + 255) / 256, 256, 0, stream>>>(W, Wh, 4096);

        // CSR build
        int eblocks = (n_edges + 255) / 256;
        edge_count<<<eblocks, 256, 0, stream>>>(dst, deg, n_edges);
        scan_a<<<nblocks_scan, 256, 0, stream>>>(deg, off, bsum, n_nodes);
        scan_b<<<1, 256, 0, stream>>>(bsum, nblocks_scan);
        scan_c<<<nblocks_scan, 256, 0, stream>>>(deg, bsum, off, cursor, n_nodes);
        edge_fill<<<eblocks, 256, 0, stream>>>(src, dst, cursor, edge_src, n_edges);

        // gather (bf16 in/out)
        sage_gather_bf16<<<(n_nodes + 3) / 4, 256, 0, stream>>>(
            xh, edge_src, off, deg, ah, n_nodes);

        // MFMA GEMM
        sage_gemm_mfma<<<(n_nodes + 63) / 64, 256, 0, stream>>>(
            xh, ah, Wh, b, out, n_nodes);
    } else if (csr_ok) {
        hipMemsetAsync(deg, 0, (size_t)n_nodes * sizeof(int), stream);

        int eblocks = (n_edges + 255) / 256;
        edge_count<<<eblocks, 256, 0, stream>>>(dst, deg, n_edges);
        scan_a<<<nblocks_scan, 256, 0, stream>>>(deg, off, bsum, n_nodes);
        scan_b<<<1, 256, 0, stream>>>(bsum, nblocks_scan);
        scan_c<<<nblocks_scan, 256, 0, stream>>>(deg, bsum, off, cursor, n_nodes);
        edge_fill<<<eblocks, 256, 0, stream>>>(src, dst, cursor, edge_src, n_edges);

        sage_gather<<<(n_nodes + 3) / 4, 256, 0, stream>>>(
            x, edge_src, off, deg, out, n_nodes);

        int blocks = (n_nodes + NT - 1) / NT;
        sage_gemm<<<blocks, 256, 0, stream>>>(x, W, b, out, out, n_nodes);
    } else {
        hipMemsetAsync(d_out, 0, (size_t)out_size * sizeof(float), stream);
        hipMemsetAsync(deg, 0, (size_t)n_nodes * sizeof(int), stream);
        long long total = (long long)n_edges * 32;
        int blocks = (int)((total + 255) / 256);
        sage_scatter<<<blocks, 256, 0, stream>>>(x, src, dst, out, deg, n_edges);
        int fblocks = (n_nodes * 32 + 255) / 256;
        sage_finalize<<<fblocks, 256, 0, stream>>>(x, deg, out, n_nodes);
        int gb = (n_nodes + NT - 1) / NT;
        sage_gemm<<<gb, 256, 0, stream>>>(x, W, b, out, out, n_nodes);
    }
}

// Round 11
// 153.946 us; speedup vs baseline: 7.5085x; 1.0670x over previous
//
#include <hip/hip_runtime.h>

// GraphSAGE layer: out = relu([x, mean-agg(x[src]->dst)] @ W^T + b)
// N=50000 nodes, E=600000 edges, D=128.
//
// Round 11: bf16 + MFMA path with widened gather.
//   gather v2: 4 edges per wave-iteration, 16B/lane dwordx4 loads (1KB/wave),
//   cross-group shfl_xor reduce. Everything else = round-10 proven kernels.
// Fallbacks: fp32 CSR path then fp-atomic path.

#define D 128
#define NT 32
#define NTT 16

typedef short bf16x8 __attribute__((ext_vector_type(8)));
typedef float f32x4 __attribute__((ext_vector_type(4)));

__device__ __forceinline__ unsigned bf16_rne(float f) {
    unsigned u = __float_as_uint(f);
    return (u + 0x7FFFu + ((u >> 16) & 1u)) >> 16;
}
__device__ __forceinline__ unsigned pack2(float lo, float hi) {
    return bf16_rne(lo) | (bf16_rne(hi) << 16);
}

// ------------- fused fp32 -> bf16 conversion for x and W -------------

__global__ __launch_bounds__(256) void convert_k(
    const float* __restrict__ x, const float* __restrict__ W,
    unsigned short* __restrict__ xh, unsigned short* __restrict__ Wh,
    int x8, int w8)
{
    int i = blockIdx.x * 256 + threadIdx.x;
    const float4* I;
    uint4* O;
    int k;
    if (i < x8) { I = (const float4*)x; O = (uint4*)xh; k = i; }
    else { k = i - x8; if (k >= w8) return; I = (const float4*)W; O = (uint4*)Wh; }
    float4 a = I[2 * k], c = I[2 * k + 1];
    uint4 r;
    r.x = pack2(a.x, a.y); r.y = pack2(a.z, a.w);
    r.z = pack2(c.x, c.y); r.w = pack2(c.z, c.w);
    O[k] = r;
}

// ---------------- CSR build ----------------

__global__ __launch_bounds__(256) void edge_count(
    const int* __restrict__ dst, int* deg, int n_edges)
{
    int e = blockIdx.x * 256 + threadIdx.x;
    if (e < n_edges) atomicAdd(deg + dst[e], 1);
}

__global__ __launch_bounds__(256) void scan_a(
    const int* __restrict__ deg, int* off, int* bsum, int n)
{
    __shared__ int tmp[256];
    int i = blockIdx.x * 256 + threadIdx.x;
    int v = (i < n) ? deg[i] : 0;
    tmp[threadIdx.x] = v;
    __syncthreads();
    for (int s = 1; s < 256; s <<= 1) {
        int t = (threadIdx.x >= s) ? tmp[threadIdx.x - s] : 0;
        __syncthreads();
        tmp[threadIdx.x] += t;
        __syncthreads();
    }
    if (i < n) off[i] = tmp[threadIdx.x];
    if (threadIdx.x == 255) bsum[blockIdx.x] = tmp[255];
}

__global__ __launch_bounds__(256) void scan_b(int* bsum, int nb)
{
    __shared__ int tmp[256];
    int v = (threadIdx.x < nb) ? bsum[threadIdx.x] : 0;
    tmp[threadIdx.x] = v;
    __syncthreads();
    for (int s = 1; s < 256; s <<= 1) {
        int t = (threadIdx.x >= s) ? tmp[threadIdx.x - s] : 0;
        __syncthreads();
        tmp[threadIdx.x] += t;
        __syncthreads();
    }
    if (threadIdx.x < nb) bsum[threadIdx.x] = tmp[threadIdx.x];
}

__global__ __launch_bounds__(256) void scan_c(
    const int* __restrict__ deg, const int* __restrict__ bsum,
    int* off, int* cursor, int n)
{
    int i = blockIdx.x * 256 + threadIdx.x;
    if (i >= n) return;
    int add = (blockIdx.x > 0) ? bsum[blockIdx.x - 1] : 0;
    int e = off[i] - deg[i] + add;
    off[i] = e;
    cursor[i] = e;
}

__global__ __launch_bounds__(256) void edge_fill(
    const int* __restrict__ src, const int* __restrict__ dst,
    int* cursor, int* edge_src, int n_edges)
{
    int e = blockIdx.x * 256 + threadIdx.x;
    if (e < n_edges) {
        int p = atomicAdd(cursor + dst[e], 1);
        edge_src[p] = src[e];
    }
}

// -------- gather v2: wave/node, 4 edges/iter, 16B/lane, shfl reduce --------

__global__ __launch_bounds__(256) void sage_gather_bf16(
    const unsigned short* __restrict__ xh, const int* __restrict__ edge_src,
    const int* __restrict__ off, const int* __restrict__ deg,
    unsigned short* __restrict__ ah, int n_nodes)
{
    int wid  = threadIdx.x >> 6;
    int lane = threadIdx.x & 63;
    int n = blockIdx.x * 4 + wid;
    if (n >= n_nodes) return;
    int dg   = deg[n];
    int base = off[n];
    int g    = lane >> 4;          // edge sub-group 0..3
    int dl   = (lane & 15) * 8;    // bf16 slice start in row

    float s[8] = {0.f, 0.f, 0.f, 0.f, 0.f, 0.f, 0.f, 0.f};
    for (int j0 = 0; j0 < dg; j0 += 4) {
        int j = j0 + g;
        if (j < dg) {
            int sidx = edge_src[base + j];
            uint4 a = *(const uint4*)(xh + (long long)sidx * 128 + dl);
            s[0] += __uint_as_float(a.x << 16);
            s[1] += __uint_as_float(a.x & 0xFFFF0000u);
            s[2] += __uint_as_float(a.y << 16);
            s[3] += __uint_as_float(a.y & 0xFFFF0000u);
            s[4] += __uint_as_float(a.z << 16);
            s[5] += __uint_as_float(a.z & 0xFFFF0000u);
            s[6] += __uint_as_float(a.w << 16);
            s[7] += __uint_as_float(a.w & 0xFFFF0000u);
        }
    }
#pragma unroll
    for (int k = 0; k < 8; ++k) {   // sum the 4 groups (lanes xor 16, 32)
        s[k] += __shfl_xor(s[k], 16, 64);
        s[k] += __shfl_xor(s[k], 32, 64);
    }
    if (g == 0) {                   // lanes 0..15 write the 256B row
        uint4 r;
        if (dg > 0) {
            float inv = 1.0f / (float)dg;
            r.x = pack2(s[0] * inv, s[1] * inv);
            r.y = pack2(s[2] * inv, s[3] * inv);
            r.z = pack2(s[4] * inv, s[5] * inv);
            r.w = pack2(s[6] * inv, s[7] * inv);
        } else {
            r = *(const uint4*)(xh + (long long)n * 128 + dl);
        }
        *(uint4*)(ah + (long long)n * 128 + dl) = r;
    }
}

// ---------------- MFMA GEMM (round-10 proven, unchanged) ----------------

__global__ __launch_bounds__(256) void sage_gemm_mfma(
    const unsigned short* __restrict__ xh, const unsigned short* __restrict__ ah,
    const unsigned short* __restrict__ Wh, const float* __restrict__ bias,
    float* __restrict__ out, int n_nodes)
{
    int wid  = threadIdx.x >> 6;
    int lane = threadIdx.x & 63;
    int m0   = blockIdx.x * 64 + wid * 16;
    int arow = m0 + (lane & 15);
    if (arow >= n_nodes) arow = n_nodes - 1;   // clamp loads; stores guarded
    int ka = (lane >> 4) * 8;
    int jn = lane & 15;

    f32x4 acc[8] = {};

    const unsigned short* xr = xh + (long long)arow * 128;
    const unsigned short* ar = ah + (long long)arow * 128;

#pragma unroll
    for (int ks = 0; ks < 4; ++ks) {           // k = 0..127 (x half)
        bf16x8 af = *(const bf16x8*)(xr + ks * 32 + ka);
#pragma unroll
        for (int nt = 0; nt < 8; ++nt) {
            bf16x8 bf = *(const bf16x8*)(Wh + (long long)(nt * 16 + jn) * 256 + ks * 32 + ka);
            acc[nt] = __builtin_amdgcn_mfma_f32_16x16x32_bf16(af, bf, acc[nt], 0, 0, 0);
        }
    }
#pragma unroll
    for (int ks = 0; ks < 4; ++ks) {           // k = 128..255 (agg half)
        bf16x8 af = *(const bf16x8*)(ar + ks * 32 + ka);
#pragma unroll
        for (int nt = 0; nt < 8; ++nt) {
            bf16x8 bf = *(const bf16x8*)(Wh + (long long)(nt * 16 + jn) * 256 + 128 + ks * 32 + ka);
            acc[nt] = __builtin_amdgcn_mfma_f32_16x16x32_bf16(af, bf, acc[nt], 0, 0, 0);
        }
    }

    int orow0 = m0 + (lane >> 4) * 4;
#pragma unroll
    for (int nt = 0; nt < 8; ++nt) {
        int col = nt * 16 + jn;
        float bj = bias[col];
#pragma unroll
        for (int r = 0; r < 4; ++r) {
            int row = orow0 + r;
            if (row < n_nodes) {
                float v = acc[nt][r] + bj;
                out[(long long)row * 128 + col] = v > 0.f ? v : 0.f;
            }
        }
    }
}

// ---------------- fp32 fallback kernels (round-8 proven) ----------------

__global__ __launch_bounds__(256) void sage_gather(
    const float* __restrict__ x, const int* __restrict__ edge_src,
    const int* __restrict__ off, const int* __restrict__ deg,
    float* __restrict__ agg, int n_nodes)
{
    int wid  = threadIdx.x >> 6;
    int lane = threadIdx.x & 63;
    int n = blockIdx.x * 4 + wid;
    if (n >= n_nodes) return;
    int dg   = deg[n];
    int base = off[n];
    const float2* X2 = (const float2*)x;

    float sx = 0.f, sy = 0.f;
    int j = 0;
    for (; j + 1 < dg; j += 2) {
        int s0 = edge_src[base + j];
        int s1 = edge_src[base + j + 1];
        float2 a = X2[(long long)s0 * 64 + lane];
        float2 c = X2[(long long)s1 * 64 + lane];
        sx += a.x + c.x;
        sy += a.y + c.y;
    }
    if (j < dg) {
        float2 a = X2[(long long)edge_src[base + j] * 64 + lane];
        sx += a.x; sy += a.y;
    }
    float2 r;
    if (dg > 0) {
        float inv = 1.0f / (float)dg;
        r.x = sx * inv; r.y = sy * inv;
    } else {
        r = X2[(long long)n * 64 + lane];
    }
    ((float2*)agg)[(long long)n * 64 + lane] = r;
}

__global__ __launch_bounds__(256) void sage_scatter(
    const float* __restrict__ x, const int* __restrict__ src,
    const int* __restrict__ dst, float* out_sum, int* deg, int n_edges)
{
    long long gid = (long long)blockIdx.x * 256 + threadIdx.x;
    long long total = (long long)n_edges * 32;
    if (gid >= total) return;
    int e  = (int)(gid >> 5);
    int d4 = (int)(gid & 31);
    int s  = src[e];
    int dd = dst[e];
    float4 xv = ((const float4*)x)[s * 32 + d4];
    float* o = out_sum + (long long)dd * D + d4 * 4;
    atomicAdd(o + 0, xv.x);
    atomicAdd(o + 1, xv.y);
    atomicAdd(o + 2, xv.z);
    atomicAdd(o + 3, xv.w);
    if (d4 == 0) atomicAdd(deg + dd, 1);
}

__global__ __launch_bounds__(256) void sage_finalize(
    const float* __restrict__ x, const int* __restrict__ deg,
    float* out, int n_nodes)
{
    int gid = blockIdx.x * 256 + threadIdx.x;
    int total = n_nodes * 32;
    if (gid >= total) return;
    int n = gid >> 5;
    int dg = deg[n];
    float4 v = ((float4*)out)[gid];
    if (dg > 0) {
        float inv = 1.0f / (float)dg;
        v.x *= inv; v.y *= inv; v.z *= inv; v.w *= inv;
    } else {
        v = ((const float4*)x)[gid];
    }
    ((float4*)out)[gid] = v;
}

__global__ __launch_bounds__(256) void sage_gemm(
    const float* __restrict__ x, const float* __restrict__ W,
    const float* __restrict__ b, const float* agg, float* out, int n_nodes)
{
    __shared__ float4 sx[NT * 32];
    __shared__ float4 sa[NT * 32];

    int tid = threadIdx.x;
    int base_row = blockIdx.x * NT;

    for (int i = tid; i < NT * 32; i += 256) {
        int r = i >> 5, c = i & 31;
        int n = base_row + r; if (n >= n_nodes) n = n_nodes - 1;
        sx[i] = ((const float4*)x)[(long long)n * 32 + c];
        sa[i] = ((const float4*)agg)[(long long)n * 32 + c];
    }
    __syncthreads();

    int j   = tid & 127;
    int sub = tid >> 7;
    int rbase = sub * NTT;

    const float4* W4 = (const float4*)W;
    float acc[NTT];
#pragma unroll
    for (int i = 0; i < NTT; ++i) acc[i] = 0.f;

#pragma unroll 4
    for (int k4 = 0; k4 < 32; ++k4) {
        float4 wx = W4[j * 64 + k4];
        float4 wa = W4[j * 64 + 32 + k4];
#pragma unroll
        for (int nn = 0; nn < NTT; ++nn) {
            float4 hx = sx[(rbase + nn) * 32 + k4];
            float4 ha = sa[(rbase + nn) * 32 + k4];
            acc[nn] += wx.x * hx.x + wx.y * hx.y + wx.z * hx.z + wx.w * hx.w
                     + wa.x * ha.x + wa.y * ha.y + wa.z * ha.z + wa.w * ha.w;
        }
    }

    float bj = b[j];
#pragma unroll
    for (int nn = 0; nn < NTT; ++nn) {
        int n = base_row + rbase + nn;
        if (n < n_nodes) {
            float v = acc[nn] + bj;
            out[(long long)n * D + j] = v > 0.f ? v : 0.f;
        }
    }
}

extern "C" void kernel_launch(void* const* d_in, const int* in_sizes, int n_in,
                              void* d_out, int out_size, void* d_ws, size_t ws_size,
                              hipStream_t stream) {
    const float* x  = (const float*)d_in[0];
    const float* W  = (const float*)d_in[1];
    const float* b  = (const float*)d_in[2];
    const int* src  = (const int*)d_in[3];
    const int* dst  = (const int*)d_in[4];
    float* out = (float*)d_out;

    int n_nodes = in_sizes[0] / D;
    int n_edges = in_sizes[3];

    int n_pad = (n_nodes + 255) & ~255;
    int e_pad = (n_edges + 3) & ~3;
    int nblocks_scan = (n_nodes + 255) / 256;

    // ws layout (ints): deg | off | cursor | bsum(1024) | edge_src(e_pad)
    //   then (bf16 path): x_bf16 (N*128 u16) | agg_bf16 (N*128 u16) | W_bf16 (32768 u16)
    size_t need_csr  = ((size_t)3 * n_pad + 1024 + (size_t)e_pad) * sizeof(int);
    size_t need_bf16 = need_csr + ((size_t)n_nodes * D * 2 + 32768) * sizeof(unsigned short);
    bool scan_ok = (nblocks_scan <= 256);
    bool bf16_ok = scan_ok && (ws_size >= need_bf16);
    bool csr_ok  = scan_ok && (ws_size >= need_csr);

    int* deg = (int*)d_ws;
    int* off      = deg + n_pad;
    int* cursor   = off + n_pad;
    int* bsum     = cursor + n_pad;
    int* edge_src = bsum + 1024;

    if (bf16_ok) {
        unsigned short* xh = (unsigned short*)(edge_src + e_pad);
        unsigned short* ah = xh + (size_t)n_nodes * D;
        unsigned short* Wh = ah + (size_t)n_nodes * D;

        hipMemsetAsync(deg, 0, (size_t)n_nodes * sizeof(int), stream);

        // fused conversions (x then W)
        int x8 = n_nodes * D / 8;
        int w8 = 4096;
        convert_k<<<(x8 + w8 + 255) / 256, 256, 0, stream>>>(x, W, xh, Wh, x8, w8);

        // CSR build
        int eblocks = (n_edges + 255) / 256;
        edge_count<<<eblocks, 256, 0, stream>>>(dst, deg, n_edges);
        scan_a<<<nblocks_scan, 256, 0, stream>>>(deg, off, bsum, n_nodes);
        scan_b<<<1, 256, 0, stream>>>(bsum, nblocks_scan);
        scan_c<<<nblocks_scan, 256, 0, stream>>>(deg, bsum, off, cursor, n_nodes);
        edge_fill<<<eblocks, 256, 0, stream>>>(src, dst, cursor, edge_src, n_edges);

        // gather v2 (bf16 in/out, 4 edges/iter)
        sage_gather_bf16<<<(n_nodes + 3) / 4, 256, 0, stream>>>(
            xh, edge_src, off, deg, ah, n_nodes);

        // MFMA GEMM
        sage_gemm_mfma<<<(n_nodes + 63) / 64, 256, 0, stream>>>(
            xh, ah, Wh, b, out, n_nodes);
    } else if (csr_ok) {
        hipMemsetAsync(deg, 0, (size_t)n_nodes * sizeof(int), stream);

        int eblocks = (n_edges + 255) / 256;
        edge_count<<<eblocks, 256, 0, stream>>>(dst, deg, n_edges);
        scan_a<<<nblocks_scan, 256, 0, stream>>>(deg, off, bsum, n_nodes);
        scan_b<<<1, 256, 0, stream>>>(bsum, nblocks_scan);
        scan_c<<<nblocks_scan, 256, 0, stream>>>(deg, bsum, off, cursor, n_nodes);
        edge_fill<<<eblocks, 256, 0, stream>>>(src, dst, cursor, edge_src, n_edges);

        sage_gather<<<(n_nodes + 3) / 4, 256, 0, stream>>>(
            x, edge_src, off, deg, out, n_nodes);

        int blocks = (n_nodes + NT - 1) / NT;
        sage_gemm<<<blocks, 256, 0, stream>>>(x, W, b, out, out, n_nodes);
    } else {
        hipMemsetAsync(d_out, 0, (size_t)out_size * sizeof(float), stream);
        hipMemsetAsync(deg, 0, (size_t)n_nodes * sizeof(int), stream);
        long long total = (long long)n_edges * 32;
        int blocks = (int)((total + 255) / 256);
        sage_scatter<<<blocks, 256, 0, stream>>>(x, src, dst, out, deg, n_edges);
        int fblocks = (n_nodes * 32 + 255) / 256;
        sage_finalize<<<fblocks, 256, 0, stream>>>(x, deg, out, n_nodes);
        int gb = (n_nodes + NT - 1) / NT;
        sage_gemm<<<gb, 256, 0, stream>>>(x, W, b, out, out, n_nodes);
    }
}

// Round 12
// 137.307 us; speedup vs baseline: 8.4184x; 1.1212x over previous
//
#include <hip/hip_runtime.h>

// GraphSAGE layer: out = relu([x, mean-agg(x[src]->dst)] @ W^T + b)
// N=50000 nodes, E=600000 edges, D=128.
//
// Round 12: fix the two 43us sinks found in round-11 counters:
//  (a) gemm B-frags were 64-address gathers (lane stride 512B) -> latency-bound
//      at MfmaUtil 2.6%. Now W is pre-permuted into fragment order (w_to_frag)
//      so B-loads are lane-contiguous coalesced 1KB reads.
//  (b) hipMemsetAsync(deg, 200KB) cost ~43us of launch/fill overhead ->
//      deg is now zeroed inside convert_k.
// Fallbacks: fp32 CSR path then fp-atomic path (proven rounds 2/8).

#define D 128
#define NT 32
#define NTT 16

typedef short bf16x8 __attribute__((ext_vector_type(8)));
typedef float f32x4 __attribute__((ext_vector_type(4)));

__device__ __forceinline__ unsigned bf16_rne(float f) {
    unsigned u = __float_as_uint(f);
    return (u + 0x7FFFu + ((u >> 16) & 1u)) >> 16;
}
__device__ __forceinline__ unsigned pack2(float lo, float hi) {
    return bf16_rne(lo) | (bf16_rne(hi) << 16);
}

// ------- fused fp32->bf16 conversion for x and W, + zero deg -------

__global__ __launch_bounds__(256) void convert_k(
    const float* __restrict__ x, const float* __restrict__ W,
    unsigned short* __restrict__ xh, unsigned short* __restrict__ Wh,
    int* __restrict__ deg, int ndeg4, int x8, int w8)
{
    int i = blockIdx.x * 256 + threadIdx.x;
    if (i < ndeg4) ((int4*)deg)[i] = make_int4(0, 0, 0, 0);
    const float4* I;
    uint4* O;
    int k;
    if (i < x8) { I = (const float4*)x; O = (uint4*)xh; k = i; }
    else { k = i - x8; if (k >= w8) return; I = (const float4*)W; O = (uint4*)Wh; }
    float4 a = I[2 * k], c = I[2 * k + 1];
    uint4 r;
    r.x = pack2(a.x, a.y); r.y = pack2(a.z, a.w);
    r.z = pack2(c.x, c.y); r.w = pack2(c.z, c.w);
    O[k] = r;
}

// ------- permute Wh (row-major [128][256]) into MFMA fragment order -------
// Wf[(nt*8+ksg)*64 + lane] (16B units) = Wh[nt*16+(lane&15)][ksg*32+(lane>>4)*8 ..+8]

__global__ __launch_bounds__(256) void w_to_frag(
    const unsigned short* __restrict__ Wh, unsigned short* __restrict__ Wf)
{
    int t = blockIdx.x * 256 + threadIdx.x;   // 0..4095
    int f = t >> 6;
    int l = t & 63;
    int nt = f >> 3, ksg = f & 7;
    int row = nt * 16 + (l & 15);
    int kk  = ksg * 32 + (l >> 4) * 8;
    *(uint4*)(Wf + t * 8) = *(const uint4*)(Wh + row * 256 + kk);
}

// ---------------- CSR build ----------------

__global__ __launch_bounds__(256) void edge_count(
    const int* __restrict__ dst, int* deg, int n_edges)
{
    int e = blockIdx.x * 256 + threadIdx.x;
    if (e < n_edges) atomicAdd(deg + dst[e], 1);
}

__global__ __launch_bounds__(256) void scan_a(
    const int* __restrict__ deg, int* off, int* bsum, int n)
{
    __shared__ int tmp[256];
    int i = blockIdx.x * 256 + threadIdx.x;
    int v = (i < n) ? deg[i] : 0;
    tmp[threadIdx.x] = v;
    __syncthreads();
    for (int s = 1; s < 256; s <<= 1) {
        int t = (threadIdx.x >= s) ? tmp[threadIdx.x - s] : 0;
        __syncthreads();
        tmp[threadIdx.x] += t;
        __syncthreads();
    }
    if (i < n) off[i] = tmp[threadIdx.x];
    if (threadIdx.x == 255) bsum[blockIdx.x] = tmp[255];
}

__global__ __launch_bounds__(256) void scan_b(int* bsum, int nb)
{
    __shared__ int tmp[256];
    int v = (threadIdx.x < nb) ? bsum[threadIdx.x] : 0;
    tmp[threadIdx.x] = v;
    __syncthreads();
    for (int s = 1; s < 256; s <<= 1) {
        int t = (threadIdx.x >= s) ? tmp[threadIdx.x - s] : 0;
        __syncthreads();
        tmp[threadIdx.x] += t;
        __syncthreads();
    }
    if (threadIdx.x < nb) bsum[threadIdx.x] = tmp[threadIdx.x];
}

__global__ __launch_bounds__(256) void scan_c(
    const int* __restrict__ deg, const int* __restrict__ bsum,
    int* off, int* cursor, int n)
{
    int i = blockIdx.x * 256 + threadIdx.x;
    if (i >= n) return;
    int add = (blockIdx.x > 0) ? bsum[blockIdx.x - 1] : 0;
    int e = off[i] - deg[i] + add;
    off[i] = e;
    cursor[i] = e;
}

__global__ __launch_bounds__(256) void edge_fill(
    const int* __restrict__ src, const int* __restrict__ dst,
    int* cursor, int* edge_src, int n_edges)
{
    int e = blockIdx.x * 256 + threadIdx.x;
    if (e < n_edges) {
        int p = atomicAdd(cursor + dst[e], 1);
        edge_src[p] = src[e];
    }
}

// -------- gather: wave/node, 4 edges/iter, 16B/lane, shfl reduce --------

__global__ __launch_bounds__(256) void sage_gather_bf16(
    const unsigned short* __restrict__ xh, const int* __restrict__ edge_src,
    const int* __restrict__ off, const int* __restrict__ deg,
    unsigned short* __restrict__ ah, int n_nodes)
{
    int wid  = threadIdx.x >> 6;
    int lane = threadIdx.x & 63;
    int n = blockIdx.x * 4 + wid;
    if (n >= n_nodes) return;
    int dg   = deg[n];
    int base = off[n];
    int g    = lane >> 4;          // edge sub-group 0..3
    int dl   = (lane & 15) * 8;    // bf16 slice start in row

    float s[8] = {0.f, 0.f, 0.f, 0.f, 0.f, 0.f, 0.f, 0.f};
    for (int j0 = 0; j0 < dg; j0 += 4) {
        int j = j0 + g;
        if (j < dg) {
            int sidx = edge_src[base + j];
            uint4 a = *(const uint4*)(xh + (long long)sidx * 128 + dl);
            s[0] += __uint_as_float(a.x << 16);
            s[1] += __uint_as_float(a.x & 0xFFFF0000u);
            s[2] += __uint_as_float(a.y << 16);
            s[3] += __uint_as_float(a.y & 0xFFFF0000u);
            s[4] += __uint_as_float(a.z << 16);
            s[5] += __uint_as_float(a.z & 0xFFFF0000u);
            s[6] += __uint_as_float(a.w << 16);
            s[7] += __uint_as_float(a.w & 0xFFFF0000u);
        }
    }
#pragma unroll
    for (int k = 0; k < 8; ++k) {
        s[k] += __shfl_xor(s[k], 16, 64);
        s[k] += __shfl_xor(s[k], 32, 64);
    }
    if (g == 0) {
        uint4 r;
        if (dg > 0) {
            float inv = 1.0f / (float)dg;
            r.x = pack2(s[0] * inv, s[1] * inv);
            r.y = pack2(s[2] * inv, s[3] * inv);
            r.z = pack2(s[4] * inv, s[5] * inv);
            r.w = pack2(s[6] * inv, s[7] * inv);
        } else {
            r = *(const uint4*)(xh + (long long)n * 128 + dl);
        }
        *(uint4*)(ah + (long long)n * 128 + dl) = r;
    }
}

// ---------------- MFMA GEMM with fragment-ordered W ----------------
// A-frag: lane holds h[m0+(lane&15)][ks*32+(lane>>4)*8 ..+8)
// B-frag: WF[(nt*8+ksg)*64 + lane]  (lane-contiguous, coalesced)
// C/D: col = lane&15, row = m0+(lane>>4)*4+reg   [verified rounds 10-11]

__global__ __launch_bounds__(256) void sage_gemm_mfma(
    const unsigned short* __restrict__ xh, const unsigned short* __restrict__ ah,
    const unsigned short* __restrict__ Wf, const float* __restrict__ bias,
    float* __restrict__ out, int n_nodes)
{
    int wid  = threadIdx.x >> 6;
    int lane = threadIdx.x & 63;
    int m0   = blockIdx.x * 64 + wid * 16;
    int arow = m0 + (lane & 15);
    if (arow >= n_nodes) arow = n_nodes - 1;   // clamp loads; stores guarded
    int ka = (lane >> 4) * 8;

    f32x4 acc[8] = {};

    const unsigned short* xr = xh + (long long)arow * 128;
    const unsigned short* ar = ah + (long long)arow * 128;
    const bf16x8* WF = (const bf16x8*)Wf;

#pragma unroll
    for (int ks = 0; ks < 4; ++ks) {           // k = 0..127 (x half)
        bf16x8 af = *(const bf16x8*)(xr + ks * 32 + ka);
#pragma unroll
        for (int nt = 0; nt < 8; ++nt) {
            bf16x8 bf = WF[(nt * 8 + ks) * 64 + lane];
            acc[nt] = __builtin_amdgcn_mfma_f32_16x16x32_bf16(af, bf, acc[nt], 0, 0, 0);
        }
    }
#pragma unroll
    for (int ks = 0; ks < 4; ++ks) {           // k = 128..255 (agg half)
        bf16x8 af = *(const bf16x8*)(ar + ks * 32 + ka);
#pragma unroll
        for (int nt = 0; nt < 8; ++nt) {
            bf16x8 bf = WF[(nt * 8 + 4 + ks) * 64 + lane];
            acc[nt] = __builtin_amdgcn_mfma_f32_16x16x32_bf16(af, bf, acc[nt], 0, 0, 0);
        }
    }

    int jn = lane & 15;
    int orow0 = m0 + (lane >> 4) * 4;
#pragma unroll
    for (int nt = 0; nt < 8; ++nt) {
        int col = nt * 16 + jn;
        float bj = bias[col];
#pragma unroll
        for (int r = 0; r < 4; ++r) {
            int row = orow0 + r;
            if (row < n_nodes) {
                float v = acc[nt][r] + bj;
                out[(long long)row * 128 + col] = v > 0.f ? v : 0.f;
            }
        }
    }
}

// ---------------- fp32 fallback kernels (round-8 proven) ----------------

__global__ __launch_bounds__(256) void sage_gather(
    const float* __restrict__ x, const int* __restrict__ edge_src,
    const int* __restrict__ off, const int* __restrict__ deg,
    float* __restrict__ agg, int n_nodes)
{
    int wid  = threadIdx.x >> 6;
    int lane = threadIdx.x & 63;
    int n = blockIdx.x * 4 + wid;
    if (n >= n_nodes) return;
    int dg   = deg[n];
    int base = off[n];
    const float2* X2 = (const float2*)x;

    float sx = 0.f, sy = 0.f;
    int j = 0;
    for (; j + 1 < dg; j += 2) {
        int s0 = edge_src[base + j];
        int s1 = edge_src[base + j + 1];
        float2 a = X2[(long long)s0 * 64 + lane];
        float2 c = X2[(long long)s1 * 64 + lane];
        sx += a.x + c.x;
        sy += a.y + c.y;
    }
    if (j < dg) {
        float2 a = X2[(long long)edge_src[base + j] * 64 + lane];
        sx += a.x; sy += a.y;
    }
    float2 r;
    if (dg > 0) {
        float inv = 1.0f / (float)dg;
        r.x = sx * inv; r.y = sy * inv;
    } else {
        r = X2[(long long)n * 64 + lane];
    }
    ((float2*)agg)[(long long)n * 64 + lane] = r;
}

__global__ __launch_bounds__(256) void sage_scatter(
    const float* __restrict__ x, const int* __restrict__ src,
    const int* __restrict__ dst, float* out_sum, int* deg, int n_edges)
{
    long long gid = (long long)blockIdx.x * 256 + threadIdx.x;
    long long total = (long long)n_edges * 32;
    if (gid >= total) return;
    int e  = (int)(gid >> 5);
    int d4 = (int)(gid & 31);
    int s  = src[e];
    int dd = dst[e];
    float4 xv = ((const float4*)x)[s * 32 + d4];
    float* o = out_sum + (long long)dd * D + d4 * 4;
    atomicAdd(o + 0, xv.x);
    atomicAdd(o + 1, xv.y);
    atomicAdd(o + 2, xv.z);
    atomicAdd(o + 3, xv.w);
    if (d4 == 0) atomicAdd(deg + dd, 1);
}

__global__ __launch_bounds__(256) void sage_finalize(
    const float* __restrict__ x, const int* __restrict__ deg,
    float* out, int n_nodes)
{
    int gid = blockIdx.x * 256 + threadIdx.x;
    int total = n_nodes * 32;
    if (gid >= total) return;
    int n = gid >> 5;
    int dg = deg[n];
    float4 v = ((float4*)out)[gid];
    if (dg > 0) {
        float inv = 1.0f / (float)dg;
        v.x *= inv; v.y *= inv; v.z *= inv; v.w *= inv;
    } else {
        v = ((const float4*)x)[gid];
    }
    ((float4*)out)[gid] = v;
}

__global__ __launch_bounds__(256) void sage_gemm(
    const float* __restrict__ x, const float* __restrict__ W,
    const float* __restrict__ b, const float* agg, float* out, int n_nodes)
{
    __shared__ float4 sx[NT * 32];
    __shared__ float4 sa[NT * 32];

    int tid = threadIdx.x;
    int base_row = blockIdx.x * NT;

    for (int i = tid; i < NT * 32; i += 256) {
        int r = i >> 5, c = i & 31;
        int n = base_row + r; if (n >= n_nodes) n = n_nodes - 1;
        sx[i] = ((const float4*)x)[(long long)n * 32 + c];
        sa[i] = ((const float4*)agg)[(long long)n * 32 + c];
    }
    __syncthreads();

    int j   = tid & 127;
    int sub = tid >> 7;
    int rbase = sub * NTT;

    const float4* W4 = (const float4*)W;
    float acc[NTT];
#pragma unroll
    for (int i = 0; i < NTT; ++i) acc[i] = 0.f;

#pragma unroll 4
    for (int k4 = 0; k4 < 32; ++k4) {
        float4 wx = W4[j * 64 + k4];
        float4 wa = W4[j * 64 + 32 + k4];
#pragma unroll
        for (int nn = 0; nn < NTT; ++nn) {
            float4 hx = sx[(rbase + nn) * 32 + k4];
            float4 ha = sa[(rbase + nn) * 32 + k4];
            acc[nn] += wx.x * hx.x + wx.y * hx.y + wx.z * hx.z + wx.w * hx.w
                     + wa.x * ha.x + wa.y * ha.y + wa.z * ha.z + wa.w * ha.w;
        }
    }

    float bj = b[j];
#pragma unroll
    for (int nn = 0; nn < NTT; ++nn) {
        int n = base_row + rbase + nn;
        if (n < n_nodes) {
            float v = acc[nn] + bj;
            out[(long long)n * D + j] = v > 0.f ? v : 0.f;
        }
    }
}

extern "C" void kernel_launch(void* const* d_in, const int* in_sizes, int n_in,
                              void* d_out, int out_size, void* d_ws, size_t ws_size,
                              hipStream_t stream) {
    const float* x  = (const float*)d_in[0];
    const float* W  = (const float*)d_in[1];
    const float* b  = (const float*)d_in[2];
    const int* src  = (const int*)d_in[3];
    const int* dst  = (const int*)d_in[4];
    float* out = (float*)d_out;

    int n_nodes = in_sizes[0] / D;
    int n_edges = in_sizes[3];

    int n_pad = (n_nodes + 255) & ~255;
    int e_pad = (n_edges + 3) & ~3;
    int nblocks_scan = (n_nodes + 255) / 256;

    // ws layout (ints): deg | off | cursor | bsum(1024) | edge_src(e_pad)
    //   then (bf16 path): x_bf16 (N*128) | agg_bf16 (N*128) | W_bf16 (32768) | W_frag (32768)
    size_t need_csr  = ((size_t)3 * n_pad + 1024 + (size_t)e_pad) * sizeof(int);
    size_t need_bf16 = need_csr + ((size_t)n_nodes * D * 2 + 65536) * sizeof(unsigned short);
    bool scan_ok = (nblocks_scan <= 256);
    bool bf16_ok = scan_ok && (ws_size >= need_bf16);
    bool csr_ok  = scan_ok && (ws_size >= need_csr);

    int* deg = (int*)d_ws;
    int* off      = deg + n_pad;
    int* cursor   = off + n_pad;
    int* bsum     = cursor + n_pad;
    int* edge_src = bsum + 1024;

    if (bf16_ok) {
        unsigned short* xh = (unsigned short*)(edge_src + e_pad);
        unsigned short* ah = xh + (size_t)n_nodes * D;
        unsigned short* Wh = ah + (size_t)n_nodes * D;
        unsigned short* Wf = Wh + 32768;

        // fused conversions (x then W) + deg zeroing (replaces 43us memset)
        int x8 = n_nodes * D / 8;
        int w8 = 4096;
        int ndeg4 = (n_nodes + 3) / 4;
        convert_k<<<(x8 + w8 + 255) / 256, 256, 0, stream>>>(
            x, W, xh, Wh, deg, ndeg4, x8, w8);

        // W -> fragment order (4096 threads)
        w_to_frag<<<16, 256, 0, stream>>>(Wh, Wf);

        // CSR build
        int eblocks = (n_edges + 255) / 256;
        edge_count<<<eblocks, 256, 0, stream>>>(dst, deg, n_edges);
        scan_a<<<nblocks_scan, 256, 0, stream>>>(deg, off, bsum, n_nodes);
        scan_b<<<1, 256, 0, stream>>>(bsum, nblocks_scan);
        scan_c<<<nblocks_scan, 256, 0, stream>>>(deg, bsum, off, cursor, n_nodes);
        edge_fill<<<eblocks, 256, 0, stream>>>(src, dst, cursor, edge_src, n_edges);

        // gather (bf16 in/out, 4 edges/iter)
        sage_gather_bf16<<<(n_nodes + 3) / 4, 256, 0, stream>>>(
            xh, edge_src, off, deg, ah, n_nodes);

        // MFMA GEMM (fragment-ordered W)
        sage_gemm_mfma<<<(n_nodes + 63) / 64, 256, 0, stream>>>(
            xh, ah, Wf, b, out, n_nodes);
    } else if (csr_ok) {
        hipMemsetAsync(deg, 0, (size_t)n_nodes * sizeof(int), stream);

        int eblocks = (n_edges + 255) / 256;
        edge_count<<<eblocks, 256, 0, stream>>>(dst, deg, n_edges);
        scan_a<<<nblocks_scan, 256, 0, stream>>>(deg, off, bsum, n_nodes);
        scan_b<<<1, 256, 0, stream>>>(bsum, nblocks_scan);
        scan_c<<<nblocks_scan, 256, 0, stream>>>(deg, bsum, off, cursor, n_nodes);
        edge_fill<<<eblocks, 256, 0, stream>>>(src, dst, cursor, edge_src, n_edges);

        sage_gather<<<(n_nodes + 3) / 4, 256, 0, stream>>>(
            x, edge_src, off, deg, out, n_nodes);

        int blocks = (n_nodes + NT - 1) / NT;
        sage_gemm<<<blocks, 256, 0, stream>>>(x, W, b, out, out, n_nodes);
    } else {
        hipMemsetAsync(d_out, 0, (size_t)out_size * sizeof(float), stream);
        hipMemsetAsync(deg, 0, (size_t)n_nodes * sizeof(int), stream);
        long long total = (long long)n_edges * 32;
        int blocks = (int)((total + 255) / 256);
        sage_scatter<<<blocks, 256, 0, stream>>>(x, src, dst, out, deg, n_edges);
        int fblocks = (n_nodes * 32 + 255) / 256;
        sage_finalize<<<fblocks, 256, 0, stream>>>(x, deg, out, n_nodes);
        int gb = (n_nodes + NT - 1) / NT;
        sage_gemm<<<gb, 256, 0, stream>>>(x, W, b, out, out, n_nodes);
    }
}

// Round 13
// 115.223 us; speedup vs baseline: 10.0319x; 1.1917x over previous
//
#include <hip/hip_runtime.h>

// GraphSAGE layer: out = relu([x, mean-agg(x[src]->dst)] @ W^T + b)
// N=50000 nodes, E=600000 edges, D=128.
//
// Round 13: XCD-sharded CSR build.
//  - count_slot: per-edge atomicAdd into shard s=blockIdx&7 (XCD-local L2 lines,
//    no cross-XCD ping-pong), records slot[e]=(p<<3)|s. Replaces edge_count AND
//    the atomic half of edge_fill.
//  - combine: 8-shard prefix per node -> deg + in-place shard bases.
//  - scan_a/b/c2: exclusive scan of deg -> off; c2 adds off into shard bases.
//  - fill2: edge_src[base[s][dst]+p] = src  -- NO atomics.
// gather + MFMA gemm unchanged (proven rounds 10-12).
// Fallbacks: fp32 CSR path then fp-atomic path.

#define D 128
#define NT 32
#define NTT 16

typedef short bf16x8 __attribute__((ext_vector_type(8)));
typedef float f32x4 __attribute__((ext_vector_type(4)));

__device__ __forceinline__ unsigned bf16_rne(float f) {
    unsigned u = __float_as_uint(f);
    return (u + 0x7FFFu + ((u >> 16) & 1u)) >> 16;
}
__device__ __forceinline__ unsigned pack2(float lo, float hi) {
    return bf16_rne(lo) | (bf16_rne(hi) << 16);
}

// ------- fused fp32->bf16 conversion for x and W, + zero dshard -------

__global__ __launch_bounds__(256) void convert_k(
    const float* __restrict__ x, const float* __restrict__ W,
    unsigned short* __restrict__ xh, unsigned short* __restrict__ Wh,
    int* __restrict__ dshard, int ndz4, int x8, int w8)
{
    int i = blockIdx.x * 256 + threadIdx.x;
    if (i < ndz4) ((int4*)dshard)[i] = make_int4(0, 0, 0, 0);
    const float4* I;
    uint4* O;
    int k;
    if (i < x8) { I = (const float4*)x; O = (uint4*)xh; k = i; }
    else { k = i - x8; if (k >= w8) return; I = (const float4*)W; O = (uint4*)Wh; }
    float4 a = I[2 * k], c = I[2 * k + 1];
    uint4 r;
    r.x = pack2(a.x, a.y); r.y = pack2(a.z, a.w);
    r.z = pack2(c.x, c.y); r.w = pack2(c.z, c.w);
    O[k] = r;
}

// ------- permute Wh (row-major [128][256]) into MFMA fragment order -------

__global__ __launch_bounds__(256) void w_to_frag(
    const unsigned short* __restrict__ Wh, unsigned short* __restrict__ Wf)
{
    int t = blockIdx.x * 256 + threadIdx.x;   // 0..4095
    int f = t >> 6;
    int l = t & 63;
    int nt = f >> 3, ksg = f & 7;
    int row = nt * 16 + (l & 15);
    int kk  = ksg * 32 + (l >> 4) * 8;
    *(uint4*)(Wf + t * 8) = *(const uint4*)(Wh + row * 256 + kk);
}

// ---------------- sharded CSR build ----------------

__global__ __launch_bounds__(256) void count_slot(
    const int* __restrict__ dst, int* dshard, int* __restrict__ slot,
    int n_pad, int n_edges)
{
    int e = blockIdx.x * 256 + threadIdx.x;
    if (e >= n_edges) return;
    int s = blockIdx.x & 7;                    // ~XCD-local shard
    int p = atomicAdd(dshard + s * n_pad + dst[e], 1);
    slot[e] = (p << 3) | s;
}

__global__ __launch_bounds__(256) void combine_k(
    int* dshard, int* __restrict__ deg, int n_pad, int n)
{
    int i = blockIdx.x * 256 + threadIdx.x;
    if (i >= n) return;
    int run = 0;
#pragma unroll
    for (int s = 0; s < 8; ++s) {
        int c = dshard[s * n_pad + i];
        dshard[s * n_pad + i] = run;
        run += c;
    }
    deg[i] = run;
}

__global__ __launch_bounds__(256) void scan_a(
    const int* __restrict__ deg, int* off, int* bsum, int n)
{
    __shared__ int tmp[256];
    int i = blockIdx.x * 256 + threadIdx.x;
    int v = (i < n) ? deg[i] : 0;
    tmp[threadIdx.x] = v;
    __syncthreads();
    for (int s = 1; s < 256; s <<= 1) {
        int t = (threadIdx.x >= s) ? tmp[threadIdx.x - s] : 0;
        __syncthreads();
        tmp[threadIdx.x] += t;
        __syncthreads();
    }
    if (i < n) off[i] = tmp[threadIdx.x];
    if (threadIdx.x == 255) bsum[blockIdx.x] = tmp[255];
}

__global__ __launch_bounds__(256) void scan_b(int* bsum, int nb)
{
    __shared__ int tmp[256];
    int v = (threadIdx.x < nb) ? bsum[threadIdx.x] : 0;
    tmp[threadIdx.x] = v;
    __syncthreads();
    for (int s = 1; s < 256; s <<= 1) {
        int t = (threadIdx.x >= s) ? tmp[threadIdx.x - s] : 0;
        __syncthreads();
        tmp[threadIdx.x] += t;
        __syncthreads();
    }
    if (threadIdx.x < nb) bsum[threadIdx.x] = tmp[threadIdx.x];
}

// off -> global exclusive; add off into the 8 shard bases.
__global__ __launch_bounds__(256) void scan_c2(
    const int* __restrict__ deg, const int* __restrict__ bsum,
    int* off, int* dshard, int n_pad, int n)
{
    int i = blockIdx.x * 256 + threadIdx.x;
    if (i >= n) return;
    int add = (blockIdx.x > 0) ? bsum[blockIdx.x - 1] : 0;
    int e = off[i] - deg[i] + add;
    off[i] = e;
#pragma unroll
    for (int s = 0; s < 8; ++s) dshard[s * n_pad + i] += e;
}

// atomic-free scatter: position fully determined by (shard base, slot).
__global__ __launch_bounds__(256) void fill2(
    const int* __restrict__ src, const int* __restrict__ dst,
    const int* __restrict__ slot, const int* __restrict__ dshard,
    int* __restrict__ edge_src, int n_pad, int n_edges)
{
    int e = blockIdx.x * 256 + threadIdx.x;
    if (e >= n_edges) return;
    int sp = slot[e];
    int pos = dshard[(sp & 7) * n_pad + dst[e]] + (sp >> 3);
    edge_src[pos] = src[e];
}

// -------- gather: wave/node, 4 edges/iter, 16B/lane, shfl reduce --------

__global__ __launch_bounds__(256) void sage_gather_bf16(
    const unsigned short* __restrict__ xh, const int* __restrict__ edge_src,
    const int* __restrict__ off, const int* __restrict__ deg,
    unsigned short* __restrict__ ah, int n_nodes)
{
    int wid  = threadIdx.x >> 6;
    int lane = threadIdx.x & 63;
    int n = blockIdx.x * 4 + wid;
    if (n >= n_nodes) return;
    int dg   = deg[n];
    int base = off[n];
    int g    = lane >> 4;          // edge sub-group 0..3
    int dl   = (lane & 15) * 8;    // bf16 slice start in row

    float s[8] = {0.f, 0.f, 0.f, 0.f, 0.f, 0.f, 0.f, 0.f};
    for (int j0 = 0; j0 < dg; j0 += 4) {
        int j = j0 + g;
        if (j < dg) {
            int sidx = edge_src[base + j];
            uint4 a = *(const uint4*)(xh + (long long)sidx * 128 + dl);
            s[0] += __uint_as_float(a.x << 16);
            s[1] += __uint_as_float(a.x & 0xFFFF0000u);
            s[2] += __uint_as_float(a.y << 16);
            s[3] += __uint_as_float(a.y & 0xFFFF0000u);
            s[4] += __uint_as_float(a.z << 16);
            s[5] += __uint_as_float(a.z & 0xFFFF0000u);
            s[6] += __uint_as_float(a.w << 16);
            s[7] += __uint_as_float(a.w & 0xFFFF0000u);
        }
    }
#pragma unroll
    for (int k = 0; k < 8; ++k) {
        s[k] += __shfl_xor(s[k], 16, 64);
        s[k] += __shfl_xor(s[k], 32, 64);
    }
    if (g == 0) {
        uint4 r;
        if (dg > 0) {
            float inv = 1.0f / (float)dg;
            r.x = pack2(s[0] * inv, s[1] * inv);
            r.y = pack2(s[2] * inv, s[3] * inv);
            r.z = pack2(s[4] * inv, s[5] * inv);
            r.w = pack2(s[6] * inv, s[7] * inv);
        } else {
            r = *(const uint4*)(xh + (long long)n * 128 + dl);
        }
        *(uint4*)(ah + (long long)n * 128 + dl) = r;
    }
}

// ---------------- MFMA GEMM with fragment-ordered W (proven) ----------------

__global__ __launch_bounds__(256) void sage_gemm_mfma(
    const unsigned short* __restrict__ xh, const unsigned short* __restrict__ ah,
    const unsigned short* __restrict__ Wf, const float* __restrict__ bias,
    float* __restrict__ out, int n_nodes)
{
    int wid  = threadIdx.x >> 6;
    int lane = threadIdx.x & 63;
    int m0   = blockIdx.x * 64 + wid * 16;
    int arow = m0 + (lane & 15);
    if (arow >= n_nodes) arow = n_nodes - 1;   // clamp loads; stores guarded
    int ka = (lane >> 4) * 8;

    f32x4 acc[8] = {};

    const unsigned short* xr = xh + (long long)arow * 128;
    const unsigned short* ar = ah + (long long)arow * 128;
    const bf16x8* WF = (const bf16x8*)Wf;

#pragma unroll
    for (int ks = 0; ks < 4; ++ks) {           // k = 0..127 (x half)
        bf16x8 af = *(const bf16x8*)(xr + ks * 32 + ka);
#pragma unroll
        for (int nt = 0; nt < 8; ++nt) {
            bf16x8 bf = WF[(nt * 8 + ks) * 64 + lane];
            acc[nt] = __builtin_amdgcn_mfma_f32_16x16x32_bf16(af, bf, acc[nt], 0, 0, 0);
        }
    }
#pragma unroll
    for (int ks = 0; ks < 4; ++ks) {           // k = 128..255 (agg half)
        bf16x8 af = *(const bf16x8*)(ar + ks * 32 + ka);
#pragma unroll
        for (int nt = 0; nt < 8; ++nt) {
            bf16x8 bf = WF[(nt * 8 + 4 + ks) * 64 + lane];
            acc[nt] = __builtin_amdgcn_mfma_f32_16x16x32_bf16(af, bf, acc[nt], 0, 0, 0);
        }
    }

    int jn = lane & 15;
    int orow0 = m0 + (lane >> 4) * 4;
#pragma unroll
    for (int nt = 0; nt < 8; ++nt) {
        int col = nt * 16 + jn;
        float bj = bias[col];
#pragma unroll
        for (int r = 0; r < 4; ++r) {
            int row = orow0 + r;
            if (row < n_nodes) {
                float v = acc[nt][r] + bj;
                out[(long long)row * 128 + col] = v > 0.f ? v : 0.f;
            }
        }
    }
}

// ---------------- fp32 fallback kernels (round-8 proven) ----------------

__global__ __launch_bounds__(256) void edge_count(
    const int* __restrict__ dst, int* deg, int n_edges)
{
    int e = blockIdx.x * 256 + threadIdx.x;
    if (e < n_edges) atomicAdd(deg + dst[e], 1);
}

__global__ __launch_bounds__(256) void scan_c(
    const int* __restrict__ deg, const int* __restrict__ bsum,
    int* off, int* cursor, int n)
{
    int i = blockIdx.x * 256 + threadIdx.x;
    if (i >= n) return;
    int add = (blockIdx.x > 0) ? bsum[blockIdx.x - 1] : 0;
    int e = off[i] - deg[i] + add;
    off[i] = e;
    cursor[i] = e;
}

__global__ __launch_bounds__(256) void edge_fill(
    const int* __restrict__ src, const int* __restrict__ dst,
    int* cursor, int* edge_src, int n_edges)
{
    int e = blockIdx.x * 256 + threadIdx.x;
    if (e < n_edges) {
        int p = atomicAdd(cursor + dst[e], 1);
        edge_src[p] = src[e];
    }
}

__global__ __launch_bounds__(256) void sage_gather(
    const float* __restrict__ x, const int* __restrict__ edge_src,
    const int* __restrict__ off, const int* __restrict__ deg,
    float* __restrict__ agg, int n_nodes)
{
    int wid  = threadIdx.x >> 6;
    int lane = threadIdx.x & 63;
    int n = blockIdx.x * 4 + wid;
    if (n >= n_nodes) return;
    int dg   = deg[n];
    int base = off[n];
    const float2* X2 = (const float2*)x;

    float sx = 0.f, sy = 0.f;
    int j = 0;
    for (; j + 1 < dg; j += 2) {
        int s0 = edge_src[base + j];
        int s1 = edge_src[base + j + 1];
        float2 a = X2[(long long)s0 * 64 + lane];
        float2 c = X2[(long long)s1 * 64 + lane];
        sx += a.x + c.x;
        sy += a.y + c.y;
    }
    if (j < dg) {
        float2 a = X2[(long long)edge_src[base + j] * 64 + lane];
        sx += a.x; sy += a.y;
    }
    float2 r;
    if (dg > 0) {
        float inv = 1.0f / (float)dg;
        r.x = sx * inv; r.y = sy * inv;
    } else {
        r = X2[(long long)n * 64 + lane];
    }
    ((float2*)agg)[(long long)n * 64 + lane] = r;
}

__global__ __launch_bounds__(256) void sage_scatter(
    const float* __restrict__ x, const int* __restrict__ src,
    const int* __restrict__ dst, float* out_sum, int* deg, int n_edges)
{
    long long gid = (long long)blockIdx.x * 256 + threadIdx.x;
    long long total = (long long)n_edges * 32;
    if (gid >= total) return;
    int e  = (int)(gid >> 5);
    int d4 = (int)(gid & 31);
    int s  = src[e];
    int dd = dst[e];
    float4 xv = ((const float4*)x)[s * 32 + d4];
    float* o = out_sum + (long long)dd * D + d4 * 4;
    atomicAdd(o + 0, xv.x);
    atomicAdd(o + 1, xv.y);
    atomicAdd(o + 2, xv.z);
    atomicAdd(o + 3, xv.w);
    if (d4 == 0) atomicAdd(deg + dd, 1);
}

__global__ __launch_bounds__(256) void sage_finalize(
    const float* __restrict__ x, const int* __restrict__ deg,
    float* out, int n_nodes)
{
    int gid = blockIdx.x * 256 + threadIdx.x;
    int total = n_nodes * 32;
    if (gid >= total) return;
    int n = gid >> 5;
    int dg = deg[n];
    float4 v = ((float4*)out)[gid];
    if (dg > 0) {
        float inv = 1.0f / (float)dg;
        v.x *= inv; v.y *= inv; v.z *= inv; v.w *= inv;
    } else {
        v = ((const float4*)x)[gid];
    }
    ((float4*)out)[gid] = v;
}

__global__ __launch_bounds__(256) void sage_gemm(
    const float* __restrict__ x, const float* __restrict__ W,
    const float* __restrict__ b, const float* agg, float* out, int n_nodes)
{
    __shared__ float4 sx[NT * 32];
    __shared__ float4 sa[NT * 32];

    int tid = threadIdx.x;
    int base_row = blockIdx.x * NT;

    for (int i = tid; i < NT * 32; i += 256) {
        int r = i >> 5, c = i & 31;
        int n = base_row + r; if (n >= n_nodes) n = n_nodes - 1;
        sx[i] = ((const float4*)x)[(long long)n * 32 + c];
        sa[i] = ((const float4*)agg)[(long long)n * 32 + c];
    }
    __syncthreads();

    int j   = tid & 127;
    int sub = tid >> 7;
    int rbase = sub * NTT;

    const float4* W4 = (const float4*)W;
    float acc[NTT];
#pragma unroll
    for (int i = 0; i < NTT; ++i) acc[i] = 0.f;

#pragma unroll 4
    for (int k4 = 0; k4 < 32; ++k4) {
        float4 wx = W4[j * 64 + k4];
        float4 wa = W4[j * 64 + 32 + k4];
#pragma unroll
        for (int nn = 0; nn < NTT; ++nn) {
            float4 hx = sx[(rbase + nn) * 32 + k4];
            float4 ha = sa[(rbase + nn) * 32 + k4];
            acc[nn] += wx.x * hx.x + wx.y * hx.y + wx.z * hx.z + wx.w * hx.w
                     + wa.x * ha.x + wa.y * ha.y + wa.z * ha.z + wa.w * ha.w;
        }
    }

    float bj = b[j];
#pragma unroll
    for (int nn = 0; nn < NTT; ++nn) {
        int n = base_row + rbase + nn;
        if (n < n_nodes) {
            float v = acc[nn] + bj;
            out[(long long)n * D + j] = v > 0.f ? v : 0.f;
        }
    }
}

extern "C" void kernel_launch(void* const* d_in, const int* in_sizes, int n_in,
                              void* d_out, int out_size, void* d_ws, size_t ws_size,
                              hipStream_t stream) {
    const float* x  = (const float*)d_in[0];
    const float* W  = (const float*)d_in[1];
    const float* b  = (const float*)d_in[2];
    const int* src  = (const int*)d_in[3];
    const int* dst  = (const int*)d_in[4];
    float* out = (float*)d_out;

    int n_nodes = in_sizes[0] / D;
    int n_edges = in_sizes[3];

    int n_pad = (n_nodes + 255) & ~255;
    int e_pad = (n_edges + 3) & ~3;
    int nblocks_scan = (n_nodes + 255) / 256;

    // ws layout (ints): dshard(8*n_pad) | slot(e_pad) | off(n_pad) | deg(n_pad)
    //                 | bsum(1024) | edge_src(e_pad)
    //   then (bf16): x_bf16 (N*128) | agg_bf16 (N*128) | W_bf16(32768) | W_frag(32768)
    size_t need_csr  = ((size_t)10 * n_pad + 2 * (size_t)e_pad + 1024) * sizeof(int);
    size_t need_bf16 = need_csr + ((size_t)n_nodes * D * 2 + 65536) * sizeof(unsigned short);
    bool scan_ok = (nblocks_scan <= 256);
    bool bf16_ok = scan_ok && (ws_size >= need_bf16);
    bool csr_ok  = scan_ok && (ws_size >= need_csr);

    int* dshard   = (int*)d_ws;               // 8*n_pad
    int* slot     = dshard + 8 * (size_t)n_pad;
    int* off      = slot + e_pad;
    int* deg      = off + n_pad;
    int* bsum     = deg + n_pad;
    int* edge_src = bsum + 1024;

    int eblocks = (n_edges + 255) / 256;

    if (bf16_ok) {
        unsigned short* xh = (unsigned short*)(edge_src + e_pad);
        unsigned short* ah = xh + (size_t)n_nodes * D;
        unsigned short* Wh = ah + (size_t)n_nodes * D;
        unsigned short* Wf = Wh + 32768;

        // fused conversions + dshard zeroing
        int x8 = n_nodes * D / 8;
        int w8 = 4096;
        int ndz4 = (8 * n_pad) / 4;
        convert_k<<<(x8 + w8 + 255) / 256, 256, 0, stream>>>(
            x, W, xh, Wh, dshard, ndz4, x8, w8);
        w_to_frag<<<16, 256, 0, stream>>>(Wh, Wf);

        // sharded CSR build
        count_slot<<<eblocks, 256, 0, stream>>>(dst, dshard, slot, n_pad, n_edges);
        combine_k<<<nblocks_scan, 256, 0, stream>>>(dshard, deg, n_pad, n_nodes);
        scan_a<<<nblocks_scan, 256, 0, stream>>>(deg, off, bsum, n_nodes);
        scan_b<<<1, 256, 0, stream>>>(bsum, nblocks_scan);
        scan_c2<<<nblocks_scan, 256, 0, stream>>>(deg, bsum, off, dshard, n_pad, n_nodes);
        fill2<<<eblocks, 256, 0, stream>>>(src, dst, slot, dshard, edge_src, n_pad, n_edges);

        // gather + MFMA GEMM
        sage_gather_bf16<<<(n_nodes + 3) / 4, 256, 0, stream>>>(
            xh, edge_src, off, deg, ah, n_nodes);
        sage_gemm_mfma<<<(n_nodes + 63) / 64, 256, 0, stream>>>(
            xh, ah, Wf, b, out, n_nodes);
    } else if (csr_ok) {
        // fp32 CSR fallback (round-8 path, non-sharded)
        int* cursor = slot;   // reuse
        hipMemsetAsync(deg, 0, (size_t)n_nodes * sizeof(int), stream);
        edge_count<<<eblocks, 256, 0, stream>>>(dst, deg, n_edges);
        scan_a<<<nblocks_scan, 256, 0, stream>>>(deg, off, bsum, n_nodes);
        scan_b<<<1, 256, 0, stream>>>(bsum, nblocks_scan);
        scan_c<<<nblocks_scan, 256, 0, stream>>>(deg, bsum, off, cursor, n_nodes);
        edge_fill<<<eblocks, 256, 0, stream>>>(src, dst, cursor, edge_src, n_edges);
        sage_gather<<<(n_nodes + 3) / 4, 256, 0, stream>>>(
            x, edge_src, off, deg, out, n_nodes);
        int blocks = (n_nodes + NT - 1) / NT;
        sage_gemm<<<blocks, 256, 0, stream>>>(x, W, b, out, out, n_nodes);
    } else {
        hipMemsetAsync(d_out, 0, (size_t)out_size * sizeof(float), stream);
        hipMemsetAsync(deg, 0, (size_t)n_nodes * sizeof(int), stream);
        long long total = (long long)n_edges * 32;
        int blocks = (int)((total + 255) / 256);
        sage_scatter<<<blocks, 256, 0, stream>>>(x, src, dst, out, deg, n_edges);
        int fblocks = (n_nodes * 32 + 255) / 256;
        sage_finalize<<<fblocks, 256, 0, stream>>>(x, deg, out, n_nodes);
        int gb = (n_nodes + NT - 1) / NT;
        sage_gemm<<<gb, 256, 0, stream>>>(x, W, b, out, out, n_nodes);
    }
}

// Round 14
// 108.462 us; speedup vs baseline: 10.6572x; 1.0623x over previous
//
#include <hip/hip_runtime.h>

// GraphSAGE layer: out = relu([x, mean-agg(x[src]->dst)] @ W^T + b)
// N=50000 nodes, E=600000 edges, D=128.
//
// Round 14: launch-count + gather-MLP pass.
//  - convert_k now emits W directly in MFMA fragment order (w_to_frag fused,
//    Wh buffer dropped).
//  - combine_k + scan_a fused into combine_scan (deg computed in-register
//    feeds the block scan directly).
//  - gather v3: 8 edges in flight/iter (2 rows per lane), zero-filled tails.
// CSR sharded build + MFMA gemm otherwise proven (rounds 10-13).
// Fallbacks: fp32 CSR path then fp-atomic path.

#define D 128
#define NT 32
#define NTT 16

typedef short bf16x8 __attribute__((ext_vector_type(8)));
typedef float f32x4 __attribute__((ext_vector_type(4)));

__device__ __forceinline__ unsigned bf16_rne(float f) {
    unsigned u = __float_as_uint(f);
    return (u + 0x7FFFu + ((u >> 16) & 1u)) >> 16;
}
__device__ __forceinline__ unsigned pack2(float lo, float hi) {
    return bf16_rne(lo) | (bf16_rne(hi) << 16);
}

// --- fused: zero dshard + convert x -> xh + convert W -> Wf (fragment order) ---
// Wf thread t (0..4095): f=t>>6, l=t&63, nt=f>>3, ksg=f&7;
//   src = W[(nt*16+(l&15))*256 + ksg*32+(l>>4)*8 .. +8]  (8 f32 = 2 float4)

__global__ __launch_bounds__(256) void convert_k(
    const float* __restrict__ x, const float* __restrict__ W,
    unsigned short* __restrict__ xh, unsigned short* __restrict__ Wf,
    int* __restrict__ dshard, int ndz4, int x8)
{
    int i = blockIdx.x * 256 + threadIdx.x;
    if (i < ndz4) ((int4*)dshard)[i] = make_int4(0, 0, 0, 0);
    if (i < x8) {
        const float4* I = (const float4*)x;
        float4 a = I[2 * i], c = I[2 * i + 1];
        uint4 r;
        r.x = pack2(a.x, a.y); r.y = pack2(a.z, a.w);
        r.z = pack2(c.x, c.y); r.w = pack2(c.z, c.w);
        ((uint4*)xh)[i] = r;
    } else {
        int t = i - x8;
        if (t >= 4096) return;
        int f = t >> 6, l = t & 63;
        int row = (f >> 3) * 16 + (l & 15);
        int kk  = (f & 7) * 32 + (l >> 4) * 8;
        const float* Ws = W + row * 256 + kk;
        float4 a = *(const float4*)Ws, c = *(const float4*)(Ws + 4);
        uint4 r;
        r.x = pack2(a.x, a.y); r.y = pack2(a.z, a.w);
        r.z = pack2(c.x, c.y); r.w = pack2(c.z, c.w);
        ((uint4*)Wf)[t] = r;
    }
}

// ---------------- sharded CSR build ----------------

__global__ __launch_bounds__(256) void count_slot(
    const int* __restrict__ dst, int* dshard, int* __restrict__ slot,
    int n_pad, int n_edges)
{
    int e = blockIdx.x * 256 + threadIdx.x;
    if (e >= n_edges) return;
    int s = blockIdx.x & 7;                    // ~XCD-local shard
    int p = atomicAdd(dshard + s * n_pad + dst[e], 1);
    slot[e] = (p << 3) | s;
}

// fused: 8-shard prefix -> deg, + block-inclusive scan of deg -> off, bsum
__global__ __launch_bounds__(256) void combine_scan(
    int* dshard, int* __restrict__ deg, int* off, int* bsum, int n_pad, int n)
{
    __shared__ int tmp[256];
    int i = blockIdx.x * 256 + threadIdx.x;
    int run = 0;
    if (i < n) {
#pragma unroll
        for (int s = 0; s < 8; ++s) {
            int c = dshard[s * n_pad + i];
            dshard[s * n_pad + i] = run;
            run += c;
        }
        deg[i] = run;
    }
    tmp[threadIdx.x] = run;
    __syncthreads();
    for (int s = 1; s < 256; s <<= 1) {
        int t = (threadIdx.x >= s) ? tmp[threadIdx.x - s] : 0;
        __syncthreads();
        tmp[threadIdx.x] += t;
        __syncthreads();
    }
    if (i < n) off[i] = tmp[threadIdx.x];
    if (threadIdx.x == 255) bsum[blockIdx.x] = tmp[255];
}

__global__ __launch_bounds__(256) void scan_b(int* bsum, int nb)
{
    __shared__ int tmp[256];
    int v = (threadIdx.x < nb) ? bsum[threadIdx.x] : 0;
    tmp[threadIdx.x] = v;
    __syncthreads();
    for (int s = 1; s < 256; s <<= 1) {
        int t = (threadIdx.x >= s) ? tmp[threadIdx.x - s] : 0;
        __syncthreads();
        tmp[threadIdx.x] += t;
        __syncthreads();
    }
    if (threadIdx.x < nb) bsum[threadIdx.x] = tmp[threadIdx.x];
}

// off -> global exclusive; add off into the 8 shard bases.
__global__ __launch_bounds__(256) void scan_c2(
    const int* __restrict__ deg, const int* __restrict__ bsum,
    int* off, int* dshard, int n_pad, int n)
{
    int i = blockIdx.x * 256 + threadIdx.x;
    if (i >= n) return;
    int add = (blockIdx.x > 0) ? bsum[blockIdx.x - 1] : 0;
    int e = off[i] - deg[i] + add;
    off[i] = e;
#pragma unroll
    for (int s = 0; s < 8; ++s) dshard[s * n_pad + i] += e;
}

// atomic-free scatter: position fully determined by (shard base, slot).
__global__ __launch_bounds__(256) void fill2(
    const int* __restrict__ src, const int* __restrict__ dst,
    const int* __restrict__ slot, const int* __restrict__ dshard,
    int* __restrict__ edge_src, int n_pad, int n_edges)
{
    int e = blockIdx.x * 256 + threadIdx.x;
    if (e >= n_edges) return;
    int sp = slot[e];
    int pos = dshard[(sp & 7) * n_pad + dst[e]] + (sp >> 3);
    edge_src[pos] = src[e];
}

// ---- gather v3: wave/node, 8 edges in flight (2 rows/lane), shfl reduce ----

__global__ __launch_bounds__(256) void sage_gather_bf16(
    const unsigned short* __restrict__ xh, const int* __restrict__ edge_src,
    const int* __restrict__ off, const int* __restrict__ deg,
    unsigned short* __restrict__ ah, int n_nodes)
{
    int wid  = threadIdx.x >> 6;
    int lane = threadIdx.x & 63;
    int n = blockIdx.x * 4 + wid;
    if (n >= n_nodes) return;
    int dg   = deg[n];
    int base = off[n];
    int g    = lane >> 4;          // edge sub-group 0..3
    int dl   = (lane & 15) * 8;    // bf16 slice start in row

    float s[8] = {0.f, 0.f, 0.f, 0.f, 0.f, 0.f, 0.f, 0.f};
    for (int j0 = 0; j0 < dg; j0 += 8) {
        int ja = j0 + g, jb = j0 + 4 + g;
        uint4 A = make_uint4(0u, 0u, 0u, 0u), B = make_uint4(0u, 0u, 0u, 0u);
        if (ja < dg) {
            int sa = edge_src[base + ja];
            A = *(const uint4*)(xh + (long long)sa * 128 + dl);
        }
        if (jb < dg) {
            int sb = edge_src[base + jb];
            B = *(const uint4*)(xh + (long long)sb * 128 + dl);
        }
        s[0] += __uint_as_float(A.x << 16) + __uint_as_float(B.x << 16);
        s[1] += __uint_as_float(A.x & 0xFFFF0000u) + __uint_as_float(B.x & 0xFFFF0000u);
        s[2] += __uint_as_float(A.y << 16) + __uint_as_float(B.y << 16);
        s[3] += __uint_as_float(A.y & 0xFFFF0000u) + __uint_as_float(B.y & 0xFFFF0000u);
        s[4] += __uint_as_float(A.z << 16) + __uint_as_float(B.z << 16);
        s[5] += __uint_as_float(A.z & 0xFFFF0000u) + __uint_as_float(B.z & 0xFFFF0000u);
        s[6] += __uint_as_float(A.w << 16) + __uint_as_float(B.w << 16);
        s[7] += __uint_as_float(A.w & 0xFFFF0000u) + __uint_as_float(B.w & 0xFFFF0000u);
    }
#pragma unroll
    for (int k = 0; k < 8; ++k) {
        s[k] += __shfl_xor(s[k], 16, 64);
        s[k] += __shfl_xor(s[k], 32, 64);
    }
    if (g == 0) {
        uint4 r;
        if (dg > 0) {
            float inv = 1.0f / (float)dg;
            r.x = pack2(s[0] * inv, s[1] * inv);
            r.y = pack2(s[2] * inv, s[3] * inv);
            r.z = pack2(s[4] * inv, s[5] * inv);
            r.w = pack2(s[6] * inv, s[7] * inv);
        } else {
            r = *(const uint4*)(xh + (long long)n * 128 + dl);
        }
        *(uint4*)(ah + (long long)n * 128 + dl) = r;
    }
}

// ---------------- MFMA GEMM with fragment-ordered W (proven) ----------------

__global__ __launch_bounds__(256) void sage_gemm_mfma(
    const unsigned short* __restrict__ xh, const unsigned short* __restrict__ ah,
    const unsigned short* __restrict__ Wf, const float* __restrict__ bias,
    float* __restrict__ out, int n_nodes)
{
    int wid  = threadIdx.x >> 6;
    int lane = threadIdx.x & 63;
    int m0   = blockIdx.x * 64 + wid * 16;
    int arow = m0 + (lane & 15);
    if (arow >= n_nodes) arow = n_nodes - 1;   // clamp loads; stores guarded
    int ka = (lane >> 4) * 8;

    f32x4 acc[8] = {};

    const unsigned short* xr = xh + (long long)arow * 128;
    const unsigned short* ar = ah + (long long)arow * 128;
    const bf16x8* WF = (const bf16x8*)Wf;

#pragma unroll
    for (int ks = 0; ks < 4; ++ks) {           // k = 0..127 (x half)
        bf16x8 af = *(const bf16x8*)(xr + ks * 32 + ka);
#pragma unroll
        for (int nt = 0; nt < 8; ++nt) {
            bf16x8 bf = WF[(nt * 8 + ks) * 64 + lane];
            acc[nt] = __builtin_amdgcn_mfma_f32_16x16x32_bf16(af, bf, acc[nt], 0, 0, 0);
        }
    }
#pragma unroll
    for (int ks = 0; ks < 4; ++ks) {           // k = 128..255 (agg half)
        bf16x8 af = *(const bf16x8*)(ar + ks * 32 + ka);
#pragma unroll
        for (int nt = 0; nt < 8; ++nt) {
            bf16x8 bf = WF[(nt * 8 + 4 + ks) * 64 + lane];
            acc[nt] = __builtin_amdgcn_mfma_f32_16x16x32_bf16(af, bf, acc[nt], 0, 0, 0);
        }
    }

    int jn = lane & 15;
    int orow0 = m0 + (lane >> 4) * 4;
#pragma unroll
    for (int nt = 0; nt < 8; ++nt) {
        int col = nt * 16 + jn;
        float bj = bias[col];
#pragma unroll
        for (int r = 0; r < 4; ++r) {
            int row = orow0 + r;
            if (row < n_nodes) {
                float v = acc[nt][r] + bj;
                out[(long long)row * 128 + col] = v > 0.f ? v : 0.f;
            }
        }
    }
}

// ---------------- fp32 fallback kernels (round-8 proven) ----------------

__global__ __launch_bounds__(256) void edge_count(
    const int* __restrict__ dst, int* deg, int n_edges)
{
    int e = blockIdx.x * 256 + threadIdx.x;
    if (e < n_edges) atomicAdd(deg + dst[e], 1);
}

__global__ __launch_bounds__(256) void scan_a(
    const int* __restrict__ deg, int* off, int* bsum, int n)
{
    __shared__ int tmp[256];
    int i = blockIdx.x * 256 + threadIdx.x;
    int v = (i < n) ? deg[i] : 0;
    tmp[threadIdx.x] = v;
    __syncthreads();
    for (int s = 1; s < 256; s <<= 1) {
        int t = (threadIdx.x >= s) ? tmp[threadIdx.x - s] : 0;
        __syncthreads();
        tmp[threadIdx.x] += t;
        __syncthreads();
    }
    if (i < n) off[i] = tmp[threadIdx.x];
    if (threadIdx.x == 255) bsum[blockIdx.x] = tmp[255];
}

__global__ __launch_bounds__(256) void scan_c(
    const int* __restrict__ deg, const int* __restrict__ bsum,
    int* off, int* cursor, int n)
{
    int i = blockIdx.x * 256 + threadIdx.x;
    if (i >= n) return;
    int add = (blockIdx.x > 0) ? bsum[blockIdx.x - 1] : 0;
    int e = off[i] - deg[i] + add;
    off[i] = e;
    cursor[i] = e;
}

__global__ __launch_bounds__(256) void edge_fill(
    const int* __restrict__ src, const int* __restrict__ dst,
    int* cursor, int* edge_src, int n_edges)
{
    int e = blockIdx.x * 256 + threadIdx.x;
    if (e < n_edges) {
        int p = atomicAdd(cursor + dst[e], 1);
        edge_src[p] = src[e];
    }
}

__global__ __launch_bounds__(256) void sage_gather(
    const float* __restrict__ x, const int* __restrict__ edge_src,
    const int* __restrict__ off, const int* __restrict__ deg,
    float* __restrict__ agg, int n_nodes)
{
    int wid  = threadIdx.x >> 6;
    int lane = threadIdx.x & 63;
    int n = blockIdx.x * 4 + wid;
    if (n >= n_nodes) return;
    int dg   = deg[n];
    int base = off[n];
    const float2* X2 = (const float2*)x;

    float sx = 0.f, sy = 0.f;
    int j = 0;
    for (; j + 1 < dg; j += 2) {
        int s0 = edge_src[base + j];
        int s1 = edge_src[base + j + 1];
        float2 a = X2[(long long)s0 * 64 + lane];
        float2 c = X2[(long long)s1 * 64 + lane];
        sx += a.x + c.x;
        sy += a.y + c.y;
    }
    if (j < dg) {
        float2 a = X2[(long long)edge_src[base + j] * 64 + lane];
        sx += a.x; sy += a.y;
    }
    float2 r;
    if (dg > 0) {
        float inv = 1.0f / (float)dg;
        r.x = sx * inv; r.y = sy * inv;
    } else {
        r = X2[(long long)n * 64 + lane];
    }
    ((float2*)agg)[(long long)n * 64 + lane] = r;
}

__global__ __launch_bounds__(256) void sage_scatter(
    const float* __restrict__ x, const int* __restrict__ src,
    const int* __restrict__ dst, float* out_sum, int* deg, int n_edges)
{
    long long gid = (long long)blockIdx.x * 256 + threadIdx.x;
    long long total = (long long)n_edges * 32;
    if (gid >= total) return;
    int e  = (int)(gid >> 5);
    int d4 = (int)(gid & 31);
    int s  = src[e];
    int dd = dst[e];
    float4 xv = ((const float4*)x)[s * 32 + d4];
    float* o = out_sum + (long long)dd * D + d4 * 4;
    atomicAdd(o + 0, xv.x);
    atomicAdd(o + 1, xv.y);
    atomicAdd(o + 2, xv.z);
    atomicAdd(o + 3, xv.w);
    if (d4 == 0) atomicAdd(deg + dd, 1);
}

__global__ __launch_bounds__(256) void sage_finalize(
    const float* __restrict__ x, const int* __restrict__ deg,
    float* out, int n_nodes)
{
    int gid = blockIdx.x * 256 + threadIdx.x;
    int total = n_nodes * 32;
    if (gid >= total) return;
    int n = gid >> 5;
    int dg = deg[n];
    float4 v = ((float4*)out)[gid];
    if (dg > 0) {
        float inv = 1.0f / (float)dg;
        v.x *= inv; v.y *= inv; v.z *= inv; v.w *= inv;
    } else {
        v = ((const float4*)x)[gid];
    }
    ((float4*)out)[gid] = v;
}

__global__ __launch_bounds__(256) void sage_gemm(
    const float* __restrict__ x, const float* __restrict__ W,
    const float* __restrict__ b, const float* agg, float* out, int n_nodes)
{
    __shared__ float4 sx[NT * 32];
    __shared__ float4 sa[NT * 32];

    int tid = threadIdx.x;
    int base_row = blockIdx.x * NT;

    for (int i = tid; i < NT * 32; i += 256) {
        int r = i >> 5, c = i & 31;
        int n = base_row + r; if (n >= n_nodes) n = n_nodes - 1;
        sx[i] = ((const float4*)x)[(long long)n * 32 + c];
        sa[i] = ((const float4*)agg)[(long long)n * 32 + c];
    }
    __syncthreads();

    int j   = tid & 127;
    int sub = tid >> 7;
    int rbase = sub * NTT;

    const float4* W4 = (const float4*)W;
    float acc[NTT];
#pragma unroll
    for (int i = 0; i < NTT; ++i) acc[i] = 0.f;

#pragma unroll 4
    for (int k4 = 0; k4 < 32; ++k4) {
        float4 wx = W4[j * 64 + k4];
        float4 wa = W4[j * 64 + 32 + k4];
#pragma unroll
        for (int nn = 0; nn < NTT; ++nn) {
            float4 hx = sx[(rbase + nn) * 32 + k4];
            float4 ha = sa[(rbase + nn) * 32 + k4];
            acc[nn] += wx.x * hx.x + wx.y * hx.y + wx.z * hx.z + wx.w * hx.w
                     + wa.x * ha.x + wa.y * ha.y + wa.z * ha.z + wa.w * ha.w;
        }
    }

    float bj = b[j];
#pragma unroll
    for (int nn = 0; nn < NTT; ++nn) {
        int n = base_row + rbase + nn;
        if (n < n_nodes) {
            float v = acc[nn] + bj;
            out[(long long)n * D + j] = v > 0.f ? v : 0.f;
        }
    }
}

extern "C" void kernel_launch(void* const* d_in, const int* in_sizes, int n_in,
                              void* d_out, int out_size, void* d_ws, size_t ws_size,
                              hipStream_t stream) {
    const float* x  = (const float*)d_in[0];
    const float* W  = (const float*)d_in[1];
    const float* b  = (const float*)d_in[2];
    const int* src  = (const int*)d_in[3];
    const int* dst  = (const int*)d_in[4];
    float* out = (float*)d_out;

    int n_nodes = in_sizes[0] / D;
    int n_edges = in_sizes[3];

    int n_pad = (n_nodes + 255) & ~255;
    int e_pad = (n_edges + 3) & ~3;
    int nblocks_scan = (n_nodes + 255) / 256;

    // ws layout (ints): dshard(8*n_pad) | slot(e_pad) | off(n_pad) | deg(n_pad)
    //                 | bsum(1024) | edge_src(e_pad)
    //   then (bf16): x_bf16 (N*128) | agg_bf16 (N*128) | W_frag(32768)
    size_t need_csr  = ((size_t)10 * n_pad + 2 * (size_t)e_pad + 1024) * sizeof(int);
    size_t need_bf16 = need_csr + ((size_t)n_nodes * D * 2 + 32768) * sizeof(unsigned short);
    bool scan_ok = (nblocks_scan <= 256);
    bool bf16_ok = scan_ok && (ws_size >= need_bf16);
    bool csr_ok  = scan_ok && (ws_size >= need_csr);

    int* dshard   = (int*)d_ws;               // 8*n_pad
    int* slot     = dshard + 8 * (size_t)n_pad;
    int* off      = slot + e_pad;
    int* deg      = off + n_pad;
    int* bsum     = deg + n_pad;
    int* edge_src = bsum + 1024;

    int eblocks = (n_edges + 255) / 256;

    if (bf16_ok) {
        unsigned short* xh = (unsigned short*)(edge_src + e_pad);
        unsigned short* ah = xh + (size_t)n_nodes * D;
        unsigned short* Wf = ah + (size_t)n_nodes * D;

        // fused: zero dshard + x->bf16 + W->fragment-order bf16
        int x8 = n_nodes * D / 8;
        int ndz4 = (8 * n_pad) / 4;
        convert_k<<<(x8 + 4096 + 255) / 256, 256, 0, stream>>>(
            x, W, xh, Wf, dshard, ndz4, x8);

        // sharded CSR build (5 kernels)
        count_slot<<<eblocks, 256, 0, stream>>>(dst, dshard, slot, n_pad, n_edges);
        combine_scan<<<nblocks_scan, 256, 0, stream>>>(dshard, deg, off, bsum, n_pad, n_nodes);
        scan_b<<<1, 256, 0, stream>>>(bsum, nblocks_scan);
        scan_c2<<<nblocks_scan, 256, 0, stream>>>(deg, bsum, off, dshard, n_pad, n_nodes);
        fill2<<<eblocks, 256, 0, stream>>>(src, dst, slot, dshard, edge_src, n_pad, n_edges);

        // gather v3 + MFMA GEMM
        sage_gather_bf16<<<(n_nodes + 3) / 4, 256, 0, stream>>>(
            xh, edge_src, off, deg, ah, n_nodes);
        sage_gemm_mfma<<<(n_nodes + 63) / 64, 256, 0, stream>>>(
            xh, ah, Wf, b, out, n_nodes);
    } else if (csr_ok) {
        // fp32 CSR fallback (round-8 path, non-sharded)
        int* cursor = slot;   // reuse
        hipMemsetAsync(deg, 0, (size_t)n_nodes * sizeof(int), stream);
        edge_count<<<eblocks, 256, 0, stream>>>(dst, deg, n_edges);
        scan_a<<<nblocks_scan, 256, 0, stream>>>(deg, off, bsum, n_nodes);
        scan_b<<<1, 256, 0, stream>>>(bsum, nblocks_scan);
        scan_c<<<nblocks_scan, 256, 0, stream>>>(deg, bsum, off, cursor, n_nodes);
        edge_fill<<<eblocks, 256, 0, stream>>>(src, dst, cursor, edge_src, n_edges);
        sage_gather<<<(n_nodes + 3) / 4, 256, 0, stream>>>(
            x, edge_src, off, deg, out, n_nodes);
        int blocks = (n_nodes + NT - 1) / NT;
        sage_gemm<<<blocks, 256, 0, stream>>>(x, W, b, out, out, n_nodes);
    } else {
        hipMemsetAsync(d_out, 0, (size_t)out_size * sizeof(float), stream);
        hipMemsetAsync(deg, 0, (size_t)n_nodes * sizeof(int), stream);
        long long total = (long long)n_edges * 32;
        int blocks = (int)((total + 255) / 256);
        sage_scatter<<<blocks, 256, 0, stream>>>(x, src, dst, out, deg, n_edges);
        int fblocks = (n_nodes * 32 + 255) / 256;
        sage_finalize<<<fblocks, 256, 0, stream>>>(x, deg, out, n_nodes);
        int gb = (n_nodes + NT - 1) / NT;
        sage_gemm<<<gb, 256, 0, stream>>>(x, W, b, out, out, n_nodes);
    }
}